// Round 3
// baseline (2417.360 us; speedup 1.0000x reference)
//
#include <hip/hip_runtime.h>
#include <hip/hip_bf16.h>
#include <math.h>

#define B_  8
#define L_  512
#define D_  1024
#define H_  16
#define NL_ 6
#define FF_ 4096
#define S_  513
#define BS_ (B_*S_)   // 4104 rows

typedef unsigned short u16;
typedef __attribute__((ext_vector_type(8))) short    short8;
typedef __attribute__((ext_vector_type(8))) unsigned short ushort8;
typedef __attribute__((ext_vector_type(4))) float    f32x4;

__device__ __forceinline__ float b2f(u16 u) {
    return __uint_as_float(((unsigned int)u) << 16);
}
__device__ __forceinline__ u16 f2b(float f) {
    unsigned int u = __float_as_uint(f);
    u += 0x7fffu + ((u >> 16) & 1u);   // round-to-nearest-even
    return (u16)(u >> 16);
}

// direct global->LDS DMA, 16B per lane (dest = wave-uniform base + lane*16)
__device__ __forceinline__ void gld_lds16(const u16* g, u16* l) {
    __builtin_amdgcn_global_load_lds(
        (const __attribute__((address_space(1))) void*)g,
        (__attribute__((address_space(3))) void*)l, 16, 0, 0);
}

// ---------------------------------------------------------------------------
// Dtype probe (flag=1: float inputs are fp32 on device — measured round 3)
// ---------------------------------------------------------------------------
__global__ __launch_bounds__(256) void probe_kernel(const u16* __restrict__ buf,
                                                    int* __restrict__ flagp) {
    __shared__ int cnt[256];
    const int tid = threadIdx.x;
    const float a = fabsf(b2f(buf[tid]));
    cnt[tid] = (a >= 1e-8f && a <= 100.0f) ? 1 : 0;
    __syncthreads();
#pragma unroll
    for (int off = 128; off > 0; off >>= 1) {
        if (tid < off) cnt[tid] += cnt[tid + off];
        __syncthreads();
    }
    if (tid == 0) *flagp = (cnt[0] < 200) ? 1 : 0;
}

__global__ __launch_bounds__(256) void cvt_kernel(const int* __restrict__ flagp,
                                                  const void* __restrict__ s,
                                                  float* __restrict__ d, int n) {
    const int wf = *flagp;
    const int i = blockIdx.x * 256 + threadIdx.x;
    if (i < n)
        d[i] = wf ? ((const float*)s)[i] : b2f(((const u16*)s)[i]);
}

// ---------------------------------------------------------------------------
// Transpose+convert weights: Wt[n][k] (bf16) = W[k][n] (fp32 or bf16)
// 32x32 tiles, 256 threads (32x8), LDS pad +1.
// ---------------------------------------------------------------------------
__global__ __launch_bounds__(256) void transp_kernel(
    const int* __restrict__ flagp, const void* __restrict__ Wbase, size_t Woff,
    u16* __restrict__ Wt, int K, int N) {
    __shared__ float tile[32][33];
    const int wf = *flagp;
    const int tid = threadIdx.x;
    const int tx = tid & 31, ty = tid >> 5;      // 32 x 8
    const int kt = blockIdx.x * 32, nt = blockIdx.y * 32;
    const float* Wf = (const float*)Wbase + Woff;
    const u16*   Wh = (const u16*)Wbase + Woff;
#pragma unroll
    for (int p = 0; p < 4; ++p) {
        const int k = kt + ty + p * 8;
        const size_t idx = (size_t)k * N + nt + tx;
        tile[ty + p * 8][tx] = wf ? Wf[idx] : b2f(Wh[idx]);
    }
    __syncthreads();
#pragma unroll
    for (int p = 0; p < 4; ++p) {
        const int n = nt + ty + p * 8;
        Wt[(size_t)n * K + kt + tx] = f2b(tile[tx][ty + p * 8]);
    }
}

// ---------------------------------------------------------------------------
__global__ __launch_bounds__(512) void dpos_kernel(const int* __restrict__ src,
                                                   int* __restrict__ dpos) {
    const int b = blockIdx.x;
    const int i = threadIdx.x;
    __shared__ int s[L_];
    s[i] = src[b * L_ + i];
    __syncthreads();
    int r = -1;
    if (s[i] < 10) {
        int j = i + 1;
        while (j < L_ && s[j] < 10) ++j;
        r = j - i - 1;
    }
    dpos[b * L_ + i] = r;
}

// ---------------------------------------------------------------------------
// embed: writes x (fp32) and xh (bf16 copy for MFMA A-operand)
// ---------------------------------------------------------------------------
__global__ __launch_bounds__(256) void embed_kernel(
    const int* __restrict__ src, const int* __restrict__ dpos,
    const float* __restrict__ tok, const float* __restrict__ pos,
    const float* __restrict__ dig, const float* __restrict__ cls,
    float* __restrict__ x, u16* __restrict__ xh) {
    const int row = blockIdx.x;          // b*S + s
    const int b = row / S_, s = row % S_;
    const int d = threadIdx.x * 4;
    float4 o;
    if (s == 0) {
        o = *(const float4*)(cls + d);
    } else {
        float4 tv = *(const float4*)(tok + (size_t)src[b * L_ + s - 1] * D_ + d);
        float4 pv = *(const float4*)(pos + (size_t)(s - 1) * D_ + d);
        o = make_float4(tv.x + pv.x, tv.y + pv.y, tv.z + pv.z, tv.w + pv.w);
        const int dp = dpos[b * L_ + s - 1];
        if (dp >= 0) {
            float4 dv = *(const float4*)(dig + (size_t)dp * D_ + d);
            o.x += dv.x; o.y += dv.y; o.z += dv.z; o.w += dv.w;
        }
    }
    *(float4*)(x + (size_t)row * D_ + d) = o;
    ushort4 oh;
    oh.x = f2b(o.x); oh.y = f2b(o.y); oh.z = f2b(o.z); oh.w = f2b(o.w);
    *(ushort4*)(xh + (size_t)row * D_ + d) = oh;
}

// ---------------------------------------------------------------------------
// MFMA GEMM r7: C[M,N](bf16) = act( A[M,K](bf16) @ Wt[N,K]^T + bias(fp32) )
// 128x128 tile, BK=32, DOUBLE-BUFFERED LDS (2x [128][32] u16 per operand,
// 32 KB total). 2-phase schedule: issue next-tile global_load_lds BEFORE
// current tile's ds_read+MFMA; single barrier per K-step -> load latency
// hides under compute (T3 minimum 2-phase).
// Swizzle (64B rows, 4 chunks of 16B): chunk ^= (row>>1)&3 on BOTH sides
// (pre-swizzled global source + swizzled ds_read) -> <=2-way (free).
// XCD-aware chunked block swizzle (all grids %8==0 -> bijective).
// Layouts (verified m89/m91/m120): A[m=lane&15][k=quad*8+j],
// B[k=quad*8+j][n=lane&15], D: col=lane&15, row=quad*4+reg.
// ---------------------------------------------------------------------------
template <int DO_GELU>
__global__ __launch_bounds__(256) void gemm_mfma(
    const u16* __restrict__ A, const u16* __restrict__ Wt,
    const float* __restrict__ bias, u16* __restrict__ C,
    int M, int N, int K) {
    __shared__ u16 Asm[2][128 * 32];
    __shared__ u16 Bsm[2][128 * 32];
    const int tid = threadIdx.x;
    const int lane = tid & 63, wave = tid >> 6;
    const int wm = wave >> 1, wn = wave & 1;
    const int m16 = lane & 15, quad = lane >> 4;

    // XCD-aware chunked swizzle of the flattened block index
    const int gx = gridDim.x;
    const int nwg = gx * gridDim.y;        // always a multiple of 8 here
    const int bid = blockIdx.y * gx + blockIdx.x;
    const int cpx = nwg >> 3;
    const int swz = (bid & 7) * cpx + (bid >> 3);
    const int row0 = (swz / gx) * 128, col0 = (swz % gx) * 128;

    // staging decomposition: lane -> (row, 16B chunk) of a wave's 1KB slab
    const int lrow   = lane >> 2;                       // 0..15
    const int schunk = ((lane & 3) ^ ((lane >> 3) & 3)) << 3;  // u16 offset
    const int rc     = (quad ^ ((m16 >> 1) & 3)) << 3;  // frag read chunk

    f32x4 acc[4][4];
#pragma unroll
    for (int i = 0; i < 4; ++i)
#pragma unroll
        for (int j = 0; j < 4; ++j)
            acc[i][j] = (f32x4){0.f, 0.f, 0.f, 0.f};

    const int nt = K >> 5;

    // prologue: stage tile 0 into buffer 0
#pragma unroll
    for (int p = 0; p < 2; ++p) {
        const int lr = p * 64 + wave * 16 + lrow;
        int ga = row0 + lr; if (ga >= M) ga = M - 1;
        gld_lds16(A + (size_t)ga * K + schunk,
                  &Asm[0][(p * 64 + wave * 16) * 32]);
        gld_lds16(Wt + (size_t)(col0 + lr) * K + schunk,
                  &Bsm[0][(p * 64 + wave * 16) * 32]);
    }
    __syncthreads();

    int cur = 0;
    for (int t = 0; t < nt - 1; ++t) {
        // issue next-tile staging FIRST (latency hides under MFMA below)
        const int k1 = (t + 1) << 5;
#pragma unroll
        for (int p = 0; p < 2; ++p) {
            const int lr = p * 64 + wave * 16 + lrow;
            int ga = row0 + lr; if (ga >= M) ga = M - 1;
            gld_lds16(A + (size_t)ga * K + k1 + schunk,
                      &Asm[cur ^ 1][(p * 64 + wave * 16) * 32]);
            gld_lds16(Wt + (size_t)(col0 + lr) * K + k1 + schunk,
                      &Bsm[cur ^ 1][(p * 64 + wave * 16) * 32]);
        }
        // compute current tile
        short8 af[4], bf[4];
#pragma unroll
        for (int i = 0; i < 4; ++i)
            af[i] = *(const short8*)&Asm[cur][(wm * 64 + i * 16 + m16) * 32 + rc];
#pragma unroll
        for (int j = 0; j < 4; ++j)
            bf[j] = *(const short8*)&Bsm[cur][(wn * 64 + j * 16 + m16) * 32 + rc];
#pragma unroll
        for (int i = 0; i < 4; ++i)
#pragma unroll
            for (int j = 0; j < 4; ++j)
                acc[i][j] = __builtin_amdgcn_mfma_f32_16x16x32_bf16(
                    af[i], bf[j], acc[i][j], 0, 0, 0);
        __syncthreads();   // drains staging vmcnt + protects buf reuse
        cur ^= 1;
    }
    // last tile (already staged and drained)
    {
        short8 af[4], bf[4];
#pragma unroll
        for (int i = 0; i < 4; ++i)
            af[i] = *(const short8*)&Asm[cur][(wm * 64 + i * 16 + m16) * 32 + rc];
#pragma unroll
        for (int j = 0; j < 4; ++j)
            bf[j] = *(const short8*)&Bsm[cur][(wn * 64 + j * 16 + m16) * 32 + rc];
#pragma unroll
        for (int i = 0; i < 4; ++i)
#pragma unroll
            for (int j = 0; j < 4; ++j)
                acc[i][j] = __builtin_amdgcn_mfma_f32_16x16x32_bf16(
                    af[i], bf[j], acc[i][j], 0, 0, 0);
    }

    // epilogue
    float biasv[4];
#pragma unroll
    for (int j = 0; j < 4; ++j)
        biasv[j] = bias[col0 + wn * 64 + j * 16 + m16];
#pragma unroll
    for (int i = 0; i < 4; ++i) {
        const int rbaseo = row0 + wm * 64 + i * 16 + quad * 4;
#pragma unroll
        for (int reg = 0; reg < 4; ++reg) {
            const int rowg = rbaseo + reg;
            if (rowg >= M) continue;
#pragma unroll
            for (int j = 0; j < 4; ++j) {
                float t = acc[i][j][reg] + biasv[j];
                if (DO_GELU)
                    t = 0.5f * t * (1.0f + erff(t * 0.70710678118654752f));
                C[(size_t)rowg * N + col0 + wn * 64 + j * 16 + m16] = f2b(t);
            }
        }
    }
}

// ---------------------------------------------------------------------------
// MFMA attention (r5): block = (q-tile 64, head, batch), 256 thr = 4 waves.
// ---------------------------------------------------------------------------
__global__ __launch_bounds__(256) void attn_kernel(
    const u16* __restrict__ qkv, const float* __restrict__ rel,
    u16* __restrict__ outc) {
    const int qt = blockIdx.x, h = blockIdx.y, b = blockIdx.z;
    const int tid = threadIdx.x;
    const int lane = tid & 63, wave = tid >> 6;
    const int m16 = lane & 15, quad = lane >> 4;
    const int strip = wave * 16;

    __shared__ u16 Qs[64 * 72];
    __shared__ u16 Ks[64 * 72];
    __shared__ u16 Vt[64 * 72 + 48];
    __shared__ u16 Ps[64 * 72];
    __shared__ float relS[132];

    const size_t base = (size_t)(b * S_) * 3072 + h * 64;
    const int m  = tid >> 2;          // staging token 0..63
    const int d0 = (tid & 3) << 4;    // 0,16,32,48

    // stage Q tile (row-major [qrow][dim])
    {
        const int qg = qt * 64 + m;
        ushort8 v0 = {0, 0, 0, 0, 0, 0, 0, 0};
        ushort8 v1 = {0, 0, 0, 0, 0, 0, 0, 0};
        if (qg < S_) {
            const u16* gp = qkv + base + (size_t)qg * 3072;
            v0 = *(const ushort8*)(gp + d0);
            v1 = *(const ushort8*)(gp + d0 + 8);
        }
        *(ushort8*)&Qs[m * 72 + d0]     = v0;
        *(ushort8*)&Qs[m * 72 + d0 + 8] = v1;
    }
    if (tid < 129) relS[tid] = rel[tid * 16 + h];
    __syncthreads();

    const short8 qa0 = *(const short8*)&Qs[(strip + m16) * 72 + quad * 8];
    const short8 qa1 = *(const short8*)&Qs[(strip + m16) * 72 + 32 + quad * 8];

    f32x4 O[4];
#pragma unroll
    for (int n = 0; n < 4; ++n) O[n] = (f32x4){0.f, 0.f, 0.f, 0.f};
    float lrun[4] = {0.f, 0.f, 0.f, 0.f};

    for (int kt = 0; kt < 9; ++kt) {
        __syncthreads();   // prev iter's frag reads of Ks/Vt/Ps done
        // stage K (row-major) and V (transposed+skewed)
        {
            const int kg = kt * 64 + m;
            const int kvalid = (kg < S_);
            ushort8 k0 = {0, 0, 0, 0, 0, 0, 0, 0};
            ushort8 k1 = {0, 0, 0, 0, 0, 0, 0, 0};
            ushort8 w0 = {0, 0, 0, 0, 0, 0, 0, 0};
            ushort8 w1 = {0, 0, 0, 0, 0, 0, 0, 0};
            if (kvalid) {
                const u16* gk = qkv + base + (size_t)kg * 3072 + 1024;
                k0 = *(const ushort8*)(gk + d0);
                k1 = *(const ushort8*)(gk + d0 + 8);
                const u16* gv = qkv + base + (size_t)kg * 3072 + 2048;
                w0 = *(const ushort8*)(gv + d0);
                w1 = *(const ushort8*)(gv + d0 + 8);
            }
            *(ushort8*)&Ks[m * 72 + d0]     = k0;
            *(ushort8*)&Ks[m * 72 + d0 + 8] = k1;
#pragma unroll
            for (int i = 0; i < 8; ++i) {
                const int da = d0 + i;
                Vt[da * 72 + (da >> 4) * 16 + m] = (u16)w0[i];
                const int db = d0 + 8 + i;
                Vt[db * 72 + (db >> 4) * 16 + m] = (u16)w1[i];
            }
        }
        __syncthreads();

        // QK^T: sc[j] covers keys 16j..16j+15 for this wave's 16 q-rows
        f32x4 sc[4];
#pragma unroll
        for (int j = 0; j < 4; ++j) {
            const short8 kb0 = *(const short8*)&Ks[(16 * j + m16) * 72 + quad * 8];
            const short8 kb1 = *(const short8*)&Ks[(16 * j + m16) * 72 + 32 + quad * 8];
            f32x4 z = (f32x4){0.f, 0.f, 0.f, 0.f};
            z = __builtin_amdgcn_mfma_f32_16x16x32_bf16(qa0, kb0, z, 0, 0, 0);
            sc[j] = __builtin_amdgcn_mfma_f32_16x16x32_bf16(qa1, kb1, z, 0, 0, 0);
        }

        // softmax numerators (identical math to passing version), -> bf16
        const int qg0 = qt * 64 + strip + quad * 4;
        float ps[4] = {0.f, 0.f, 0.f, 0.f};
#pragma unroll
        for (int j = 0; j < 4; ++j) {
            const int kg = kt * 64 + 16 * j + m16;
            const int kvalid = (kg < S_);
#pragma unroll
            for (int reg = 0; reg < 4; ++reg) {
                int rr = kg - (qg0 + reg);
                rr = rr < -64 ? -64 : (rr > 64 ? 64 : rr);
                float s = sc[j][reg] * 0.125f + relS[rr + 64];
                s = s > 60.f ? 60.f : s;
                float pv = kvalid ? __expf(s) : 0.f;
                const u16 pb = f2b(pv);
                Ps[(strip + quad * 4 + reg) * 72 + 16 * j + m16] = pb;
                ps[reg] += b2f(pb);   // denominator from rounded P (consistent)
            }
        }
#pragma unroll
        for (int mk = 1; mk < 16; mk <<= 1) {
#pragma unroll
            for (int reg = 0; reg < 4; ++reg)
                ps[reg] += __shfl_xor(ps[reg], mk);
        }
#pragma unroll
        for (int reg = 0; reg < 4; ++reg) lrun[reg] += ps[reg];
        __syncthreads();   // Ps visible

        // PV: O[n] (dims 16n..16n+15) += P @ V
        const short8 pa0 = *(const short8*)&Ps[(strip + m16) * 72 + quad * 8];
        const short8 pa1 = *(const short8*)&Ps[(strip + m16) * 72 + 32 + quad * 8];
#pragma unroll
        for (int n = 0; n < 4; ++n) {
            const int dd = 16 * n + m16;
            const int vbase = dd * 72 + (dd >> 4) * 16;
            const short8 vb0 = *(const short8*)&Vt[vbase + quad * 8];
            const short8 vb1 = *(const short8*)&Vt[vbase + 32 + quad * 8];
            O[n] = __builtin_amdgcn_mfma_f32_16x16x32_bf16(pa0, vb0, O[n], 0, 0, 0);
            O[n] = __builtin_amdgcn_mfma_f32_16x16x32_bf16(pa1, vb1, O[n], 0, 0, 0);
        }
    }

    // epilogue: normalize + store (lrun[reg] is exactly this lane's O rows)
#pragma unroll
    for (int reg = 0; reg < 4; ++reg) {
        const int qg = qt * 64 + strip + quad * 4 + reg;
        if (qg >= S_) continue;
        const float inv = 1.0f / lrun[reg];
        u16* op = outc + (size_t)(b * S_ + qg) * D_ + h * 64;
#pragma unroll
        for (int n = 0; n < 4; ++n)
            op[16 * n + m16] = f2b(O[n][reg] * inv);
    }
}

// ---------------------------------------------------------------------------
// add_ln: x fp32 (residual) + Bv bf16 -> LN -> x fp32 AND xh bf16
// ---------------------------------------------------------------------------
__global__ __launch_bounds__(256) void add_ln_kernel(
    const float* __restrict__ A, const u16* __restrict__ Bv,
    const float* __restrict__ g, const float* __restrict__ be,
    float* __restrict__ outp, u16* __restrict__ outh) {
    const int row = blockIdx.x;
    const int tid = threadIdx.x;
    __shared__ float r1[256], r2[256];
    float4 a = *(const float4*)(A + (size_t)row * D_ + tid * 4);
    ushort4 b4 = *(const ushort4*)(Bv + (size_t)row * D_ + tid * 4);
    const float v0 = a.x + b2f(b4.x), v1 = a.y + b2f(b4.y);
    const float v2 = a.z + b2f(b4.z), v3 = a.w + b2f(b4.w);
    r1[tid] = v0 + v1 + v2 + v3;
    r2[tid] = v0 * v0 + v1 * v1 + v2 * v2 + v3 * v3;
    __syncthreads();
#pragma unroll
    for (int off = 128; off > 0; off >>= 1) {
        if (tid < off) { r1[tid] += r1[tid + off]; r2[tid] += r2[tid + off]; }
        __syncthreads();
    }
    const float mu = r1[0] * (1.0f / 1024.0f);
    const float var = r2[0] * (1.0f / 1024.0f) - mu * mu;
    const float rs = rsqrtf(var + 1e-5f);
    float4 gv = *(const float4*)(g + tid * 4);
    float4 bev = *(const float4*)(be + tid * 4);
    float4 o = make_float4((v0 - mu) * rs * gv.x + bev.x,
                           (v1 - mu) * rs * gv.y + bev.y,
                           (v2 - mu) * rs * gv.z + bev.z,
                           (v3 - mu) * rs * gv.w + bev.w);
    *(float4*)(outp + (size_t)row * D_ + tid * 4) = o;
    ushort4 oh;
    oh.x = f2b(o.x); oh.y = f2b(o.y); oh.z = f2b(o.z); oh.w = f2b(o.w);
    *(ushort4*)(outh + (size_t)row * D_ + tid * 4) = oh;
}

// ---------------------------------------------------------------------------
__global__ __launch_bounds__(256) void head_kernel(
    const int* __restrict__ flagp,
    const float* __restrict__ x, const float* __restrict__ g,
    const float* __restrict__ be, const float* __restrict__ cw,
    const float* __restrict__ cb, void* __restrict__ outp) {
    const int b = blockIdx.x, tid = threadIdx.x;
    __shared__ float xn[D_];
    __shared__ float r1[256], r2[256];
    const float* xr = x + (size_t)b * S_ * D_;
    float4 v = *(const float4*)(xr + tid * 4);
    r1[tid] = v.x + v.y + v.z + v.w;
    r2[tid] = v.x * v.x + v.y * v.y + v.z * v.z + v.w * v.w;
    __syncthreads();
#pragma unroll
    for (int off = 128; off > 0; off >>= 1) {
        if (tid < off) { r1[tid] += r1[tid + off]; r2[tid] += r2[tid + off]; }
        __syncthreads();
    }
    const float mu = r1[0] * (1.0f / 1024.0f);
    const float var = r2[0] * (1.0f / 1024.0f) - mu * mu;
    const float rs = rsqrtf(var + 1e-5f);
    float4 gv = *(const float4*)(g + tid * 4);
    float4 bev = *(const float4*)(be + tid * 4);
    xn[tid * 4 + 0] = (v.x - mu) * rs * gv.x + bev.x;
    xn[tid * 4 + 1] = (v.y - mu) * rs * gv.y + bev.y;
    xn[tid * 4 + 2] = (v.z - mu) * rs * gv.z + bev.z;
    xn[tid * 4 + 3] = (v.w - mu) * rs * gv.w + bev.w;
    __syncthreads();
    if (tid < 80) {
        float acc = cb[tid];
        for (int dd = 0; dd < D_; ++dd)
            acc = fmaf(xn[dd], cw[dd * 80 + tid], acc);
        if (*flagp) ((float*)outp)[b * 80 + tid] = acc;
        else        ((u16*)outp)[b * 80 + tid] = f2b(acc);
    }
}

// ---------------------------------------------------------------------------
extern "C" void kernel_launch(void* const* d_in, const int* in_sizes, int n_in,
                              void* d_out, int out_size, void* d_ws, size_t ws_size,
                              hipStream_t stream) {
    const int* src = (const int*)d_in[0];
    (void)in_sizes; (void)n_in; (void)out_size; (void)ws_size;

    char* p = (char*)d_ws;
    auto carve = [&](size_t bytes) {
        char* r = p; p += (bytes + 255) & ~(size_t)255; return r;
    };
    int*   flag = (int*)carve(256);
    float* x    = (float*)carve((size_t)BS_ * D_ * 4);   // fp32 residual
    u16*   xh   = (u16*)carve((size_t)BS_ * D_ * 2);     // bf16 copy of x
    u16*   big  = (u16*)carve((size_t)BS_ * FF_ * 2);    // qkv / ff1 out
    u16*   t1   = (u16*)carve((size_t)BS_ * D_ * 2);     // attn out / ff2 out
    u16*   Wt   = (u16*)carve((size_t)FF_ * D_ * 2);     // transposed weight
    int*   dpos = (int*)carve((size_t)B_ * L_ * 4);
    u16*   t2   = big;                                   // proj out (aliases)

    const int PN[17]  = {16*D_, S_*D_, L_*D_, D_,
                         NL_*3*D_, NL_*D_, NL_*129*16,
                         NL_*D_, NL_*D_, NL_*FF_, NL_*D_,
                         NL_*D_, NL_*D_, D_, D_,
                         D_*80, 80};
    const int PIN[17] = {2, 3, 4, 5, 7, 9, 10, 11, 12, 14, 16, 17, 18,
                         19, 20, 21, 22};
    float* P[17];
    {
        size_t off = 0;
        float* base = (float*)carve(1243312 * 4);
        for (int i = 0; i < 17; ++i) { P[i] = base + off; off += PN[i]; }
    }
    float *Ptok = P[0], *Ppos = P[1], *Pdig = P[2], *Pcls = P[3];
    float *Pqkvb = P[4], *Poutb = P[5], *Prel = P[6];
    float *Pln1g = P[7], *Pln1b = P[8], *Pl1b = P[9], *Pl2b = P[10];
    float *Pln2g = P[11], *Pln2b = P[12], *Pfng = P[13], *Pfnb = P[14];
    float *Pcw = P[15], *Pcb = P[16];

    probe_kernel<<<1, 256, 0, stream>>>((const u16*)d_in[6], flag);
    for (int i = 0; i < 17; ++i)
        cvt_kernel<<<(PN[i] + 255) / 256, 256, 0, stream>>>(
            flag, d_in[PIN[i]], P[i], PN[i]);

    dpos_kernel<<<B_, L_, 0, stream>>>(src, dpos);
    embed_kernel<<<BS_, 256, 0, stream>>>(src, dpos, Ptok, Ppos, Pdig, Pcls,
                                          x, xh);

    const int gy = (BS_ + 127) / 128;   // 33
    for (int l = 0; l < NL_; ++l) {
        // qkv = xh @ qkv_w + b
        transp_kernel<<<dim3(D_ / 32, 3 * D_ / 32), 256, 0, stream>>>(
            flag, d_in[6], (size_t)l * D_ * 3 * D_, Wt, D_, 3 * D_);
        gemm_mfma<0><<<dim3(3 * D_ / 128, gy), 256, 0, stream>>>(
            xh, Wt, Pqkvb + (size_t)l * 3 * D_, big, BS_, 3 * D_, D_);
        attn_kernel<<<dim3(9, H_, B_), 256, 0, stream>>>(
            big, Prel + (size_t)l * 129 * 16, t1);
        // proj = t1 @ out_w + b  -> t2 (= big region, qkv dead)
        transp_kernel<<<dim3(D_ / 32, D_ / 32), 256, 0, stream>>>(
            flag, d_in[8], (size_t)l * D_ * D_, Wt, D_, D_);
        gemm_mfma<0><<<dim3(D_ / 128, gy), 256, 0, stream>>>(
            t1, Wt, Poutb + (size_t)l * D_, t2, BS_, D_, D_);
        add_ln_kernel<<<BS_, 256, 0, stream>>>(x, t2, Pln1g + l * D_,
                                               Pln1b + l * D_, x, xh);
        // ff1 = gelu(xh @ lin1_w + b) -> big (t2 dead)
        transp_kernel<<<dim3(D_ / 32, FF_ / 32), 256, 0, stream>>>(
            flag, d_in[13], (size_t)l * D_ * FF_, Wt, D_, FF_);
        gemm_mfma<1><<<dim3(FF_ / 128, gy), 256, 0, stream>>>(
            xh, Wt, Pl1b + (size_t)l * FF_, big, BS_, FF_, D_);
        // ff2 = big @ lin2_w + b -> t1 (attn out dead)
        transp_kernel<<<dim3(FF_ / 32, D_ / 32), 256, 0, stream>>>(
            flag, d_in[15], (size_t)l * FF_ * D_, Wt, FF_, D_);
        gemm_mfma<0><<<dim3(D_ / 128, gy), 256, 0, stream>>>(
            big, Wt, Pl2b + (size_t)l * D_, t1, BS_, D_, FF_);
        add_ln_kernel<<<BS_, 256, 0, stream>>>(x, t1, Pln2g + l * D_,
                                               Pln2b + l * D_, x, xh);
    }
    head_kernel<<<B_, 256, 0, stream>>>(flag, x, Pfng, Pfnb, Pcw, Pcb, d_out);
}

// Round 4
// 2308.599 us; speedup vs baseline: 1.0471x; 1.0471x over previous
//
#include <hip/hip_runtime.h>
#include <hip/hip_bf16.h>
#include <math.h>

#define B_  8
#define L_  512
#define D_  1024
#define H_  16
#define NL_ 6
#define FF_ 4096
#define S_  513
#define BS_ (B_*S_)   // 4104 rows

typedef unsigned short u16;
typedef __attribute__((ext_vector_type(8))) short    short8;
typedef __attribute__((ext_vector_type(8))) unsigned short ushort8;
typedef __attribute__((ext_vector_type(4))) float    f32x4;

__device__ __forceinline__ float b2f(u16 u) {
    return __uint_as_float(((unsigned int)u) << 16);
}
__device__ __forceinline__ u16 f2b(float f) {
    unsigned int u = __float_as_uint(f);
    u += 0x7fffu + ((u >> 16) & 1u);   // round-to-nearest-even
    return (u16)(u >> 16);
}

// direct global->LDS DMA, 16B per lane (dest = wave-uniform base + lane*16)
__device__ __forceinline__ void gld_lds16(const u16* g, u16* l) {
    __builtin_amdgcn_global_load_lds(
        (const __attribute__((address_space(1))) void*)g,
        (__attribute__((address_space(3))) void*)l, 16, 0, 0);
}

// ---------------------------------------------------------------------------
// Dtype probe (flag=1: float inputs are fp32 on device — measured round 3)
// ---------------------------------------------------------------------------
__global__ __launch_bounds__(256) void probe_kernel(const u16* __restrict__ buf,
                                                    int* __restrict__ flagp) {
    __shared__ int cnt[256];
    const int tid = threadIdx.x;
    const float a = fabsf(b2f(buf[tid]));
    cnt[tid] = (a >= 1e-8f && a <= 100.0f) ? 1 : 0;
    __syncthreads();
#pragma unroll
    for (int off = 128; off > 0; off >>= 1) {
        if (tid < off) cnt[tid] += cnt[tid + off];
        __syncthreads();
    }
    if (tid == 0) *flagp = (cnt[0] < 200) ? 1 : 0;
}

__global__ __launch_bounds__(256) void cvt_kernel(const int* __restrict__ flagp,
                                                  const void* __restrict__ s,
                                                  float* __restrict__ d, int n) {
    const int wf = *flagp;
    const int i = blockIdx.x * 256 + threadIdx.x;
    if (i < n)
        d[i] = wf ? ((const float*)s)[i] : b2f(((const u16*)s)[i]);
}

// ---------------------------------------------------------------------------
// Transpose+convert weights: Wt[n][k] (bf16) = W[k][n] (fp32 or bf16)
// 32x32 tiles, 256 threads (32x8), LDS pad +1.
// ---------------------------------------------------------------------------
__global__ __launch_bounds__(256) void transp_kernel(
    const int* __restrict__ flagp, const void* __restrict__ Wbase, size_t Woff,
    u16* __restrict__ Wt, int K, int N) {
    __shared__ float tile[32][33];
    const int wf = *flagp;
    const int tid = threadIdx.x;
    const int tx = tid & 31, ty = tid >> 5;      // 32 x 8
    const int kt = blockIdx.x * 32, nt = blockIdx.y * 32;
    const float* Wf = (const float*)Wbase + Woff;
    const u16*   Wh = (const u16*)Wbase + Woff;
#pragma unroll
    for (int p = 0; p < 4; ++p) {
        const int k = kt + ty + p * 8;
        const size_t idx = (size_t)k * N + nt + tx;
        tile[ty + p * 8][tx] = wf ? Wf[idx] : b2f(Wh[idx]);
    }
    __syncthreads();
#pragma unroll
    for (int p = 0; p < 4; ++p) {
        const int n = nt + ty + p * 8;
        Wt[(size_t)n * K + kt + tx] = f2b(tile[tx][ty + p * 8]);
    }
}

// ---------------------------------------------------------------------------
__global__ __launch_bounds__(512) void dpos_kernel(const int* __restrict__ src,
                                                   int* __restrict__ dpos) {
    const int b = blockIdx.x;
    const int i = threadIdx.x;
    __shared__ int s[L_];
    s[i] = src[b * L_ + i];
    __syncthreads();
    int r = -1;
    if (s[i] < 10) {
        int j = i + 1;
        while (j < L_ && s[j] < 10) ++j;
        r = j - i - 1;
    }
    dpos[b * L_ + i] = r;
}

// ---------------------------------------------------------------------------
// embed: writes x (fp32) and xh (bf16 copy for MFMA A-operand)
// ---------------------------------------------------------------------------
__global__ __launch_bounds__(256) void embed_kernel(
    const int* __restrict__ src, const int* __restrict__ dpos,
    const float* __restrict__ tok, const float* __restrict__ pos,
    const float* __restrict__ dig, const float* __restrict__ cls,
    float* __restrict__ x, u16* __restrict__ xh) {
    const int row = blockIdx.x;          // b*S + s
    const int b = row / S_, s = row % S_;
    const int d = threadIdx.x * 4;
    float4 o;
    if (s == 0) {
        o = *(const float4*)(cls + d);
    } else {
        float4 tv = *(const float4*)(tok + (size_t)src[b * L_ + s - 1] * D_ + d);
        float4 pv = *(const float4*)(pos + (size_t)(s - 1) * D_ + d);
        o = make_float4(tv.x + pv.x, tv.y + pv.y, tv.z + pv.z, tv.w + pv.w);
        const int dp = dpos[b * L_ + s - 1];
        if (dp >= 0) {
            float4 dv = *(const float4*)(dig + (size_t)dp * D_ + d);
            o.x += dv.x; o.y += dv.y; o.z += dv.z; o.w += dv.w;
        }
    }
    *(float4*)(x + (size_t)row * D_ + d) = o;
    ushort4 oh;
    oh.x = f2b(o.x); oh.y = f2b(o.y); oh.z = f2b(o.z); oh.w = f2b(o.w);
    *(ushort4*)(xh + (size_t)row * D_ + d) = oh;
}

// ---------------------------------------------------------------------------
// MFMA GEMM r8: C[M,N](bf16) = act( A[M,K](bf16) @ Wt[N,K]^T + bias(fp32) )
// 128x128 tile, BK=32, double-buffered LDS (2x [128][32] u16 per operand,
// 32 KB). 2-phase schedule with COUNTED vmcnt (T4): per K-step issue next
// tile's 4 global_load_lds, then s_waitcnt vmcnt(4) (waits ONLY prev tile,
// new loads stay in flight across the raw s_barrier), ds_read+MFMA on cur
// buffer (T5 setprio), second raw s_barrier before buf reuse. No vmcnt(0)
// in the main loop (m218: counted-vs-drain0 = the whole gain).
// Swizzle (64B rows, 4 chunks of 16B): chunk ^= (row>>1)&3 on BOTH sides
// (pre-swizzled global source + swizzled ds_read) -> measured 0 conflicts.
// XCD-aware chunked block swizzle (all grids %8==0 -> bijective).
// Layouts (verified m89/m91/m120): A[m=lane&15][k=quad*8+j],
// B[k=quad*8+j][n=lane&15], D: col=lane&15, row=quad*4+reg.
// ---------------------------------------------------------------------------
template <int DO_GELU>
__global__ __launch_bounds__(256) void gemm_mfma(
    const u16* __restrict__ A, const u16* __restrict__ Wt,
    const float* __restrict__ bias, u16* __restrict__ C,
    int M, int N, int K) {
    __shared__ u16 Asm[2][128 * 32];
    __shared__ u16 Bsm[2][128 * 32];
    const int tid = threadIdx.x;
    const int lane = tid & 63, wave = tid >> 6;
    const int wm = wave >> 1, wn = wave & 1;
    const int m16 = lane & 15, quad = lane >> 4;

    // XCD-aware chunked swizzle of the flattened block index
    const int gx = gridDim.x;
    const int nwg = gx * gridDim.y;        // always a multiple of 8 here
    const int bid = blockIdx.y * gx + blockIdx.x;
    const int cpx = nwg >> 3;
    const int swz = (bid & 7) * cpx + (bid >> 3);
    const int row0 = (swz / gx) * 128, col0 = (swz % gx) * 128;

    // staging decomposition: lane -> (row, 16B chunk) of a wave's 1KB slab
    const int lrow   = lane >> 2;                       // 0..15
    const int schunk = ((lane & 3) ^ ((lane >> 3) & 3)) << 3;  // u16 offset
    const int rc     = (quad ^ ((m16 >> 1) & 3)) << 3;  // frag read chunk

    f32x4 acc[4][4];
#pragma unroll
    for (int i = 0; i < 4; ++i)
#pragma unroll
        for (int j = 0; j < 4; ++j)
            acc[i][j] = (f32x4){0.f, 0.f, 0.f, 0.f};

    const int nt = K >> 5;

    // per-wave A/B staging rows (wave-uniform LDS dest, per-lane global src)
    const int r0 = wave * 16 + lrow;           // p=0 row
    const int r1 = 64 + wave * 16 + lrow;      // p=1 row
    int ga0 = row0 + r0; if (ga0 >= M) ga0 = M - 1;
    int ga1 = row0 + r1; if (ga1 >= M) ga1 = M - 1;
    const u16* Arow0 = A + (size_t)ga0 * K + schunk;
    const u16* Arow1 = A + (size_t)ga1 * K + schunk;
    const u16* Brow0 = Wt + (size_t)(col0 + r0) * K + schunk;
    const u16* Brow1 = Wt + (size_t)(col0 + r1) * K + schunk;

    // prologue: stage tile 0 into buffer 0 (4 loads in flight)
    gld_lds16(Arow0, &Asm[0][(wave * 16) * 32]);
    gld_lds16(Brow0, &Bsm[0][(wave * 16) * 32]);
    gld_lds16(Arow1, &Asm[0][(64 + wave * 16) * 32]);
    gld_lds16(Brow1, &Bsm[0][(64 + wave * 16) * 32]);

    int cur = 0;
    for (int t = 0; t < nt - 1; ++t) {
        // 1. issue next-tile staging (stays in flight across the barrier)
        const int k1 = (t + 1) << 5;
        gld_lds16(Arow0 + k1, &Asm[cur ^ 1][(wave * 16) * 32]);
        gld_lds16(Brow0 + k1, &Bsm[cur ^ 1][(wave * 16) * 32]);
        gld_lds16(Arow1 + k1, &Asm[cur ^ 1][(64 + wave * 16) * 32]);
        gld_lds16(Brow1 + k1, &Bsm[cur ^ 1][(64 + wave * 16) * 32]);
        // 2. wait ONLY for prev tile's 4 loads; sync all waves
        asm volatile("s_waitcnt vmcnt(4)" ::: "memory");
        __builtin_amdgcn_s_barrier();
        asm volatile("" ::: "memory");
        // 3. compute current tile
        short8 af[4], bf[4];
#pragma unroll
        for (int i = 0; i < 4; ++i)
            af[i] = *(const short8*)&Asm[cur][(wm * 64 + i * 16 + m16) * 32 + rc];
#pragma unroll
        for (int j = 0; j < 4; ++j)
            bf[j] = *(const short8*)&Bsm[cur][(wn * 64 + j * 16 + m16) * 32 + rc];
        __builtin_amdgcn_s_setprio(1);
#pragma unroll
        for (int i = 0; i < 4; ++i)
#pragma unroll
            for (int j = 0; j < 4; ++j)
                acc[i][j] = __builtin_amdgcn_mfma_f32_16x16x32_bf16(
                    af[i], bf[j], acc[i][j], 0, 0, 0);
        __builtin_amdgcn_s_setprio(0);
        // 4. all waves done reading buf[cur] before next iter overwrites it
        __builtin_amdgcn_s_barrier();
        asm volatile("" ::: "memory");
        cur ^= 1;
    }
    // tail tile: drain remaining loads, sync, compute
    asm volatile("s_waitcnt vmcnt(0)" ::: "memory");
    __builtin_amdgcn_s_barrier();
    asm volatile("" ::: "memory");
    {
        short8 af[4], bf[4];
#pragma unroll
        for (int i = 0; i < 4; ++i)
            af[i] = *(const short8*)&Asm[cur][(wm * 64 + i * 16 + m16) * 32 + rc];
#pragma unroll
        for (int j = 0; j < 4; ++j)
            bf[j] = *(const short8*)&Bsm[cur][(wn * 64 + j * 16 + m16) * 32 + rc];
#pragma unroll
        for (int i = 0; i < 4; ++i)
#pragma unroll
            for (int j = 0; j < 4; ++j)
                acc[i][j] = __builtin_amdgcn_mfma_f32_16x16x32_bf16(
                    af[i], bf[j], acc[i][j], 0, 0, 0);
    }

    // epilogue
    float biasv[4];
#pragma unroll
    for (int j = 0; j < 4; ++j)
        biasv[j] = bias[col0 + wn * 64 + j * 16 + m16];
#pragma unroll
    for (int i = 0; i < 4; ++i) {
        const int rbaseo = row0 + wm * 64 + i * 16 + quad * 4;
#pragma unroll
        for (int reg = 0; reg < 4; ++reg) {
            const int rowg = rbaseo + reg;
            if (rowg >= M) continue;
#pragma unroll
            for (int j = 0; j < 4; ++j) {
                float t = acc[i][j][reg] + biasv[j];
                if (DO_GELU)
                    t = 0.5f * t * (1.0f + erff(t * 0.70710678118654752f));
                C[(size_t)rowg * N + col0 + wn * 64 + j * 16 + m16] = f2b(t);
            }
        }
    }
}

// ---------------------------------------------------------------------------
// MFMA attention (r5): block = (q-tile 64, head, batch), 256 thr = 4 waves.
// ---------------------------------------------------------------------------
__global__ __launch_bounds__(256) void attn_kernel(
    const u16* __restrict__ qkv, const float* __restrict__ rel,
    u16* __restrict__ outc) {
    const int qt = blockIdx.x, h = blockIdx.y, b = blockIdx.z;
    const int tid = threadIdx.x;
    const int lane = tid & 63, wave = tid >> 6;
    const int m16 = lane & 15, quad = lane >> 4;
    const int strip = wave * 16;

    __shared__ u16 Qs[64 * 72];
    __shared__ u16 Ks[64 * 72];
    __shared__ u16 Vt[64 * 72 + 48];
    __shared__ u16 Ps[64 * 72];
    __shared__ float relS[132];

    const size_t base = (size_t)(b * S_) * 3072 + h * 64;
    const int m  = tid >> 2;          // staging token 0..63
    const int d0 = (tid & 3) << 4;    // 0,16,32,48

    // stage Q tile (row-major [qrow][dim])
    {
        const int qg = qt * 64 + m;
        ushort8 v0 = {0, 0, 0, 0, 0, 0, 0, 0};
        ushort8 v1 = {0, 0, 0, 0, 0, 0, 0, 0};
        if (qg < S_) {
            const u16* gp = qkv + base + (size_t)qg * 3072;
            v0 = *(const ushort8*)(gp + d0);
            v1 = *(const ushort8*)(gp + d0 + 8);
        }
        *(ushort8*)&Qs[m * 72 + d0]     = v0;
        *(ushort8*)&Qs[m * 72 + d0 + 8] = v1;
    }
    if (tid < 129) relS[tid] = rel[tid * 16 + h];
    __syncthreads();

    const short8 qa0 = *(const short8*)&Qs[(strip + m16) * 72 + quad * 8];
    const short8 qa1 = *(const short8*)&Qs[(strip + m16) * 72 + 32 + quad * 8];

    f32x4 O[4];
#pragma unroll
    for (int n = 0; n < 4; ++n) O[n] = (f32x4){0.f, 0.f, 0.f, 0.f};
    float lrun[4] = {0.f, 0.f, 0.f, 0.f};

    for (int kt = 0; kt < 9; ++kt) {
        __syncthreads();   // prev iter's frag reads of Ks/Vt/Ps done
        // stage K (row-major) and V (transposed+skewed)
        {
            const int kg = kt * 64 + m;
            const int kvalid = (kg < S_);
            ushort8 k0 = {0, 0, 0, 0, 0, 0, 0, 0};
            ushort8 k1 = {0, 0, 0, 0, 0, 0, 0, 0};
            ushort8 w0 = {0, 0, 0, 0, 0, 0, 0, 0};
            ushort8 w1 = {0, 0, 0, 0, 0, 0, 0, 0};
            if (kvalid) {
                const u16* gk = qkv + base + (size_t)kg * 3072 + 1024;
                k0 = *(const ushort8*)(gk + d0);
                k1 = *(const ushort8*)(gk + d0 + 8);
                const u16* gv = qkv + base + (size_t)kg * 3072 + 2048;
                w0 = *(const ushort8*)(gv + d0);
                w1 = *(const ushort8*)(gv + d0 + 8);
            }
            *(ushort8*)&Ks[m * 72 + d0]     = k0;
            *(ushort8*)&Ks[m * 72 + d0 + 8] = k1;
#pragma unroll
            for (int i = 0; i < 8; ++i) {
                const int da = d0 + i;
                Vt[da * 72 + (da >> 4) * 16 + m] = (u16)w0[i];
                const int db = d0 + 8 + i;
                Vt[db * 72 + (db >> 4) * 16 + m] = (u16)w1[i];
            }
        }
        __syncthreads();

        // QK^T: sc[j] covers keys 16j..16j+15 for this wave's 16 q-rows
        f32x4 sc[4];
#pragma unroll
        for (int j = 0; j < 4; ++j) {
            const short8 kb0 = *(const short8*)&Ks[(16 * j + m16) * 72 + quad * 8];
            const short8 kb1 = *(const short8*)&Ks[(16 * j + m16) * 72 + 32 + quad * 8];
            f32x4 z = (f32x4){0.f, 0.f, 0.f, 0.f};
            z = __builtin_amdgcn_mfma_f32_16x16x32_bf16(qa0, kb0, z, 0, 0, 0);
            sc[j] = __builtin_amdgcn_mfma_f32_16x16x32_bf16(qa1, kb1, z, 0, 0, 0);
        }

        // softmax numerators (identical math to passing version), -> bf16
        const int qg0 = qt * 64 + strip + quad * 4;
        float ps[4] = {0.f, 0.f, 0.f, 0.f};
#pragma unroll
        for (int j = 0; j < 4; ++j) {
            const int kg = kt * 64 + 16 * j + m16;
            const int kvalid = (kg < S_);
#pragma unroll
            for (int reg = 0; reg < 4; ++reg) {
                int rr = kg - (qg0 + reg);
                rr = rr < -64 ? -64 : (rr > 64 ? 64 : rr);
                float s = sc[j][reg] * 0.125f + relS[rr + 64];
                s = s > 60.f ? 60.f : s;
                float pv = kvalid ? __expf(s) : 0.f;
                const u16 pb = f2b(pv);
                Ps[(strip + quad * 4 + reg) * 72 + 16 * j + m16] = pb;
                ps[reg] += b2f(pb);   // denominator from rounded P (consistent)
            }
        }
#pragma unroll
        for (int mk = 1; mk < 16; mk <<= 1) {
#pragma unroll
            for (int reg = 0; reg < 4; ++reg)
                ps[reg] += __shfl_xor(ps[reg], mk);
        }
#pragma unroll
        for (int reg = 0; reg < 4; ++reg) lrun[reg] += ps[reg];
        __syncthreads();   // Ps visible

        // PV: O[n] (dims 16n..16n+15) += P @ V
        const short8 pa0 = *(const short8*)&Ps[(strip + m16) * 72 + quad * 8];
        const short8 pa1 = *(const short8*)&Ps[(strip + m16) * 72 + 32 + quad * 8];
#pragma unroll
        for (int n = 0; n < 4; ++n) {
            const int dd = 16 * n + m16;
            const int vbase = dd * 72 + (dd >> 4) * 16;
            const short8 vb0 = *(const short8*)&Vt[vbase + quad * 8];
            const short8 vb1 = *(const short8*)&Vt[vbase + 32 + quad * 8];
            O[n] = __builtin_amdgcn_mfma_f32_16x16x32_bf16(pa0, vb0, O[n], 0, 0, 0);
            O[n] = __builtin_amdgcn_mfma_f32_16x16x32_bf16(pa1, vb1, O[n], 0, 0, 0);
        }
    }

    // epilogue: normalize + store (lrun[reg] is exactly this lane's O rows)
#pragma unroll
    for (int reg = 0; reg < 4; ++reg) {
        const int qg = qt * 64 + strip + quad * 4 + reg;
        if (qg >= S_) continue;
        const float inv = 1.0f / lrun[reg];
        u16* op = outc + (size_t)(b * S_ + qg) * D_ + h * 64;
#pragma unroll
        for (int n = 0; n < 4; ++n)
            op[16 * n + m16] = f2b(O[n][reg] * inv);
    }
}

// ---------------------------------------------------------------------------
// add_ln: x fp32 (residual) + Bv bf16 -> LN -> x fp32 AND xh bf16
// ---------------------------------------------------------------------------
__global__ __launch_bounds__(256) void add_ln_kernel(
    const float* __restrict__ A, const u16* __restrict__ Bv,
    const float* __restrict__ g, const float* __restrict__ be,
    float* __restrict__ outp, u16* __restrict__ outh) {
    const int row = blockIdx.x;
    const int tid = threadIdx.x;
    __shared__ float r1[256], r2[256];
    float4 a = *(const float4*)(A + (size_t)row * D_ + tid * 4);
    ushort4 b4 = *(const ushort4*)(Bv + (size_t)row * D_ + tid * 4);
    const float v0 = a.x + b2f(b4.x), v1 = a.y + b2f(b4.y);
    const float v2 = a.z + b2f(b4.z), v3 = a.w + b2f(b4.w);
    r1[tid] = v0 + v1 + v2 + v3;
    r2[tid] = v0 * v0 + v1 * v1 + v2 * v2 + v3 * v3;
    __syncthreads();
#pragma unroll
    for (int off = 128; off > 0; off >>= 1) {
        if (tid < off) { r1[tid] += r1[tid + off]; r2[tid] += r2[tid + off]; }
        __syncthreads();
    }
    const float mu = r1[0] * (1.0f / 1024.0f);
    const float var = r2[0] * (1.0f / 1024.0f) - mu * mu;
    const float rs = rsqrtf(var + 1e-5f);
    float4 gv = *(const float4*)(g + tid * 4);
    float4 bev = *(const float4*)(be + tid * 4);
    float4 o = make_float4((v0 - mu) * rs * gv.x + bev.x,
                           (v1 - mu) * rs * gv.y + bev.y,
                           (v2 - mu) * rs * gv.z + bev.z,
                           (v3 - mu) * rs * gv.w + bev.w);
    *(float4*)(outp + (size_t)row * D_ + tid * 4) = o;
    ushort4 oh;
    oh.x = f2b(o.x); oh.y = f2b(o.y); oh.z = f2b(o.z); oh.w = f2b(o.w);
    *(ushort4*)(outh + (size_t)row * D_ + tid * 4) = oh;
}

// ---------------------------------------------------------------------------
__global__ __launch_bounds__(256) void head_kernel(
    const int* __restrict__ flagp,
    const float* __restrict__ x, const float* __restrict__ g,
    const float* __restrict__ be, const float* __restrict__ cw,
    const float* __restrict__ cb, void* __restrict__ outp) {
    const int b = blockIdx.x, tid = threadIdx.x;
    __shared__ float xn[D_];
    __shared__ float r1[256], r2[256];
    const float* xr = x + (size_t)b * S_ * D_;
    float4 v = *(const float4*)(xr + tid * 4);
    r1[tid] = v.x + v.y + v.z + v.w;
    r2[tid] = v.x * v.x + v.y * v.y + v.z * v.z + v.w * v.w;
    __syncthreads();
#pragma unroll
    for (int off = 128; off > 0; off >>= 1) {
        if (tid < off) { r1[tid] += r1[tid + off]; r2[tid] += r2[tid + off]; }
        __syncthreads();
    }
    const float mu = r1[0] * (1.0f / 1024.0f);
    const float var = r2[0] * (1.0f / 1024.0f) - mu * mu;
    const float rs = rsqrtf(var + 1e-5f);
    float4 gv = *(const float4*)(g + tid * 4);
    float4 bev = *(const float4*)(be + tid * 4);
    xn[tid * 4 + 0] = (v.x - mu) * rs * gv.x + bev.x;
    xn[tid * 4 + 1] = (v.y - mu) * rs * gv.y + bev.y;
    xn[tid * 4 + 2] = (v.z - mu) * rs * gv.z + bev.z;
    xn[tid * 4 + 3] = (v.w - mu) * rs * gv.w + bev.w;
    __syncthreads();
    if (tid < 80) {
        float acc = cb[tid];
        for (int dd = 0; dd < D_; ++dd)
            acc = fmaf(xn[dd], cw[dd * 80 + tid], acc);
        if (*flagp) ((float*)outp)[b * 80 + tid] = acc;
        else        ((u16*)outp)[b * 80 + tid] = f2b(acc);
    }
}

// ---------------------------------------------------------------------------
extern "C" void kernel_launch(void* const* d_in, const int* in_sizes, int n_in,
                              void* d_out, int out_size, void* d_ws, size_t ws_size,
                              hipStream_t stream) {
    const int* src = (const int*)d_in[0];
    (void)in_sizes; (void)n_in; (void)out_size; (void)ws_size;

    char* p = (char*)d_ws;
    auto carve = [&](size_t bytes) {
        char* r = p; p += (bytes + 255) & ~(size_t)255; return r;
    };
    int*   flag = (int*)carve(256);
    float* x    = (float*)carve((size_t)BS_ * D_ * 4);   // fp32 residual
    u16*   xh   = (u16*)carve((size_t)BS_ * D_ * 2);     // bf16 copy of x
    u16*   big  = (u16*)carve((size_t)BS_ * FF_ * 2);    // qkv / ff1 out
    u16*   t1   = (u16*)carve((size_t)BS_ * D_ * 2);     // attn out / ff2 out
    u16*   Wt   = (u16*)carve((size_t)FF_ * D_ * 2);     // transposed weight
    int*   dpos = (int*)carve((size_t)B_ * L_ * 4);
    u16*   t2   = big;                                   // proj out (aliases)

    const int PN[17]  = {16*D_, S_*D_, L_*D_, D_,
                         NL_*3*D_, NL_*D_, NL_*129*16,
                         NL_*D_, NL_*D_, NL_*FF_, NL_*D_,
                         NL_*D_, NL_*D_, D_, D_,
                         D_*80, 80};
    const int PIN[17] = {2, 3, 4, 5, 7, 9, 10, 11, 12, 14, 16, 17, 18,
                         19, 20, 21, 22};
    float* P[17];
    {
        size_t off = 0;
        float* base = (float*)carve(1243312 * 4);
        for (int i = 0; i < 17; ++i) { P[i] = base + off; off += PN[i]; }
    }
    float *Ptok = P[0], *Ppos = P[1], *Pdig = P[2], *Pcls = P[3];
    float *Pqkvb = P[4], *Poutb = P[5], *Prel = P[6];
    float *Pln1g = P[7], *Pln1b = P[8], *Pl1b = P[9], *Pl2b = P[10];
    float *Pln2g = P[11], *Pln2b = P[12], *Pfng = P[13], *Pfnb = P[14];
    float *Pcw = P[15], *Pcb = P[16];

    probe_kernel<<<1, 256, 0, stream>>>((const u16*)d_in[6], flag);
    for (int i = 0; i < 17; ++i)
        cvt_kernel<<<(PN[i] + 255) / 256, 256, 0, stream>>>(
            flag, d_in[PIN[i]], P[i], PN[i]);

    dpos_kernel<<<B_, L_, 0, stream>>>(src, dpos);
    embed_kernel<<<BS_, 256, 0, stream>>>(src, dpos, Ptok, Ppos, Pdig, Pcls,
                                          x, xh);

    const int gy = (BS_ + 127) / 128;   // 33
    for (int l = 0; l < NL_; ++l) {
        // qkv = xh @ qkv_w + b
        transp_kernel<<<dim3(D_ / 32, 3 * D_ / 32), 256, 0, stream>>>(
            flag, d_in[6], (size_t)l * D_ * 3 * D_, Wt, D_, 3 * D_);
        gemm_mfma<0><<<dim3(3 * D_ / 128, gy), 256, 0, stream>>>(
            xh, Wt, Pqkvb + (size_t)l * 3 * D_, big, BS_, 3 * D_, D_);
        attn_kernel<<<dim3(9, H_, B_), 256, 0, stream>>>(
            big, Prel + (size_t)l * 129 * 16, t1);
        // proj = t1 @ out_w + b  -> t2 (= big region, qkv dead)
        transp_kernel<<<dim3(D_ / 32, D_ / 32), 256, 0, stream>>>(
            flag, d_in[8], (size_t)l * D_ * D_, Wt, D_, D_);
        gemm_mfma<0><<<dim3(D_ / 128, gy), 256, 0, stream>>>(
            t1, Wt, Poutb + (size_t)l * D_, t2, BS_, D_, D_);
        add_ln_kernel<<<BS_, 256, 0, stream>>>(x, t2, Pln1g + l * D_,
                                               Pln1b + l * D_, x, xh);
        // ff1 = gelu(xh @ lin1_w + b) -> big (t2 dead)
        transp_kernel<<<dim3(D_ / 32, FF_ / 32), 256, 0, stream>>>(
            flag, d_in[13], (size_t)l * D_ * FF_, Wt, D_, FF_);
        gemm_mfma<1><<<dim3(FF_ / 128, gy), 256, 0, stream>>>(
            xh, Wt, Pl1b + (size_t)l * FF_, big, BS_, FF_, D_);
        // ff2 = big @ lin2_w + b -> t1 (attn out dead)
        transp_kernel<<<dim3(FF_ / 32, D_ / 32), 256, 0, stream>>>(
            flag, d_in[15], (size_t)l * FF_ * D_, Wt, FF_, D_);
        gemm_mfma<0><<<dim3(D_ / 128, gy), 256, 0, stream>>>(
            big, Wt, Pl2b + (size_t)l * D_, t1, BS_, D_, FF_);
        add_ln_kernel<<<BS_, 256, 0, stream>>>(x, t1, Pln2g + l * D_,
                                               Pln2b + l * D_, x, xh);
    }
    head_kernel<<<B_, 256, 0, stream>>>(flag, x, Pfng, Pfnb, Pcw, Pcb, d_out);
}

// Round 5
// 2247.236 us; speedup vs baseline: 1.0757x; 1.0273x over previous
//
#include <hip/hip_runtime.h>
#include <hip/hip_bf16.h>
#include <math.h>

#define B_  8
#define L_  512
#define D_  1024
#define H_  16
#define NL_ 6
#define FF_ 4096
#define S_  513
#define BS_ (B_*S_)   // 4104 rows

typedef unsigned short u16;
typedef __attribute__((ext_vector_type(8))) short    short8;
typedef __attribute__((ext_vector_type(8))) unsigned short ushort8;
typedef __attribute__((ext_vector_type(4))) float    f32x4;

__device__ __forceinline__ float b2f(u16 u) {
    return __uint_as_float(((unsigned int)u) << 16);
}
__device__ __forceinline__ u16 f2b(float f) {
    unsigned int u = __float_as_uint(f);
    u += 0x7fffu + ((u >> 16) & 1u);   // round-to-nearest-even
    return (u16)(u >> 16);
}

// direct global->LDS DMA, 16B per lane (dest = wave-uniform base + lane*16)
__device__ __forceinline__ void gld_lds16(const u16* g, u16* l) {
    __builtin_amdgcn_global_load_lds(
        (const __attribute__((address_space(1))) void*)g,
        (__attribute__((address_space(3))) void*)l, 16, 0, 0);
}

// ---------------------------------------------------------------------------
// Dtype probe (flag=1: float inputs are fp32 on device — measured round 3)
// ---------------------------------------------------------------------------
__global__ __launch_bounds__(256) void probe_kernel(const u16* __restrict__ buf,
                                                    int* __restrict__ flagp) {
    __shared__ int cnt[256];
    const int tid = threadIdx.x;
    const float a = fabsf(b2f(buf[tid]));
    cnt[tid] = (a >= 1e-8f && a <= 100.0f) ? 1 : 0;
    __syncthreads();
#pragma unroll
    for (int off = 128; off > 0; off >>= 1) {
        if (tid < off) cnt[tid] += cnt[tid + off];
        __syncthreads();
    }
    if (tid == 0) *flagp = (cnt[0] < 200) ? 1 : 0;
}

__global__ __launch_bounds__(256) void cvt_kernel(const int* __restrict__ flagp,
                                                  const void* __restrict__ s,
                                                  float* __restrict__ d, int n) {
    const int wf = *flagp;
    const int i = blockIdx.x * 256 + threadIdx.x;
    if (i < n)
        d[i] = wf ? ((const float*)s)[i] : b2f(((const u16*)s)[i]);
}

// ---------------------------------------------------------------------------
// Transpose+convert weights: Wt[n][k] (bf16) = W[k][n] (fp32 or bf16)
// 32x32 tiles, 256 threads (32x8), LDS pad +1.
// ---------------------------------------------------------------------------
__global__ __launch_bounds__(256) void transp_kernel(
    const int* __restrict__ flagp, const void* __restrict__ Wbase, size_t Woff,
    u16* __restrict__ Wt, int K, int N) {
    __shared__ float tile[32][33];
    const int wf = *flagp;
    const int tid = threadIdx.x;
    const int tx = tid & 31, ty = tid >> 5;      // 32 x 8
    const int kt = blockIdx.x * 32, nt = blockIdx.y * 32;
    const float* Wf = (const float*)Wbase + Woff;
    const u16*   Wh = (const u16*)Wbase + Woff;
#pragma unroll
    for (int p = 0; p < 4; ++p) {
        const int k = kt + ty + p * 8;
        const size_t idx = (size_t)k * N + nt + tx;
        tile[ty + p * 8][tx] = wf ? Wf[idx] : b2f(Wh[idx]);
    }
    __syncthreads();
#pragma unroll
    for (int p = 0; p < 4; ++p) {
        const int n = nt + ty + p * 8;
        Wt[(size_t)n * K + kt + tx] = f2b(tile[tx][ty + p * 8]);
    }
}

// ---------------------------------------------------------------------------
__global__ __launch_bounds__(512) void dpos_kernel(const int* __restrict__ src,
                                                   int* __restrict__ dpos) {
    const int b = blockIdx.x;
    const int i = threadIdx.x;
    __shared__ int s[L_];
    s[i] = src[b * L_ + i];
    __syncthreads();
    int r = -1;
    if (s[i] < 10) {
        int j = i + 1;
        while (j < L_ && s[j] < 10) ++j;
        r = j - i - 1;
    }
    dpos[b * L_ + i] = r;
}

// ---------------------------------------------------------------------------
// embed: writes x (fp32) and xh (bf16 copy for MFMA A-operand)
// ---------------------------------------------------------------------------
__global__ __launch_bounds__(256) void embed_kernel(
    const int* __restrict__ src, const int* __restrict__ dpos,
    const float* __restrict__ tok, const float* __restrict__ pos,
    const float* __restrict__ dig, const float* __restrict__ cls,
    float* __restrict__ x, u16* __restrict__ xh) {
    const int row = blockIdx.x;          // b*S + s
    const int b = row / S_, s = row % S_;
    const int d = threadIdx.x * 4;
    float4 o;
    if (s == 0) {
        o = *(const float4*)(cls + d);
    } else {
        float4 tv = *(const float4*)(tok + (size_t)src[b * L_ + s - 1] * D_ + d);
        float4 pv = *(const float4*)(pos + (size_t)(s - 1) * D_ + d);
        o = make_float4(tv.x + pv.x, tv.y + pv.y, tv.z + pv.z, tv.w + pv.w);
        const int dp = dpos[b * L_ + s - 1];
        if (dp >= 0) {
            float4 dv = *(const float4*)(dig + (size_t)dp * D_ + d);
            o.x += dv.x; o.y += dv.y; o.z += dv.z; o.w += dv.w;
        }
    }
    *(float4*)(x + (size_t)row * D_ + d) = o;
    ushort4 oh;
    oh.x = f2b(o.x); oh.y = f2b(o.y); oh.z = f2b(o.z); oh.w = f2b(o.w);
    *(ushort4*)(xh + (size_t)row * D_ + d) = oh;
}

// ---------------------------------------------------------------------------
// MFMA GEMM r9: C[M,N](bf16) = act( A[M,K](bf16) @ Wt[N,K]^T + bias(fp32) )
// 128x128 tile, BK=32, double-buffered LDS (32 KB). T3 MINIMUM 2-PHASE
// recipe (m230-V0/m248v2, 655-682 TF @K=1024): per K-step
//   STAGE(buf^1, t+1)  ->  ds_read(buf cur) -> MFMA  ->  vmcnt(0) -> barrier
// ONE barrier per step, wait AFTER compute: next-tile load latency hides
// under this step's ds_read+MFMA. (r3/r4 waited BEFORE compute with two
// barriers -> zero effective pipeline depth; measured regression.)
// Swizzle (64B rows, 4 chunks of 16B): chunk ^= (row>>1)&3 on BOTH sides
// (pre-swizzled global source + swizzled ds_read) -> measured 0 conflicts.
// XCD-aware chunked block swizzle (all grids %8==0 -> bijective).
// Layouts (verified m89/m91/m120): A[m=lane&15][k=quad*8+j],
// B[k=quad*8+j][n=lane&15], D: col=lane&15, row=quad*4+reg.
// ---------------------------------------------------------------------------
template <int DO_GELU>
__global__ __launch_bounds__(256) void gemm_mfma(
    const u16* __restrict__ A, const u16* __restrict__ Wt,
    const float* __restrict__ bias, u16* __restrict__ C,
    int M, int N, int K) {
    __shared__ u16 Asm[2][128 * 32];
    __shared__ u16 Bsm[2][128 * 32];
    const int tid = threadIdx.x;
    const int lane = tid & 63, wave = tid >> 6;
    const int wm = wave >> 1, wn = wave & 1;
    const int m16 = lane & 15, quad = lane >> 4;

    // XCD-aware chunked swizzle of the flattened block index
    const int gx = gridDim.x;
    const int nwg = gx * gridDim.y;        // always a multiple of 8 here
    const int bid = blockIdx.y * gx + blockIdx.x;
    const int cpx = nwg >> 3;
    const int swz = (bid & 7) * cpx + (bid >> 3);
    const int row0 = (swz / gx) * 128, col0 = (swz % gx) * 128;

    // staging decomposition: lane -> (row, 16B chunk) of a wave's 1KB slab
    const int lrow   = lane >> 2;                       // 0..15
    const int schunk = ((lane & 3) ^ ((lane >> 3) & 3)) << 3;  // u16 offset
    const int rc     = (quad ^ ((m16 >> 1) & 3)) << 3;  // frag read chunk

    f32x4 acc[4][4];
#pragma unroll
    for (int i = 0; i < 4; ++i)
#pragma unroll
        for (int j = 0; j < 4; ++j)
            acc[i][j] = (f32x4){0.f, 0.f, 0.f, 0.f};

    const int nt = K >> 5;

    // per-wave A/B staging rows (wave-uniform LDS dest, per-lane global src)
    const int r0 = wave * 16 + lrow;           // p=0 row
    const int r1 = 64 + wave * 16 + lrow;      // p=1 row
    int ga0 = row0 + r0; if (ga0 >= M) ga0 = M - 1;
    int ga1 = row0 + r1; if (ga1 >= M) ga1 = M - 1;
    const u16* Arow0 = A + (size_t)ga0 * K + schunk;
    const u16* Arow1 = A + (size_t)ga1 * K + schunk;
    const u16* Brow0 = Wt + (size_t)(col0 + r0) * K + schunk;
    const u16* Brow1 = Wt + (size_t)(col0 + r1) * K + schunk;

    // prologue: stage tile 0 into buffer 0, drain, sync
    gld_lds16(Arow0, &Asm[0][(wave * 16) * 32]);
    gld_lds16(Brow0, &Bsm[0][(wave * 16) * 32]);
    gld_lds16(Arow1, &Asm[0][(64 + wave * 16) * 32]);
    gld_lds16(Brow1, &Bsm[0][(64 + wave * 16) * 32]);
    asm volatile("s_waitcnt vmcnt(0)" ::: "memory");
    __builtin_amdgcn_s_barrier();
    asm volatile("" ::: "memory");

    int cur = 0;
    for (int t = 0; t < nt - 1; ++t) {
        // 1. issue next-tile staging (latency hides under this step's compute)
        const int k1 = (t + 1) << 5;
        gld_lds16(Arow0 + k1, &Asm[cur ^ 1][(wave * 16) * 32]);
        gld_lds16(Brow0 + k1, &Bsm[cur ^ 1][(wave * 16) * 32]);
        gld_lds16(Arow1 + k1, &Asm[cur ^ 1][(64 + wave * 16) * 32]);
        gld_lds16(Brow1 + k1, &Bsm[cur ^ 1][(64 + wave * 16) * 32]);
        // 2. compute current tile (compiler manages lgkmcnt for ds_reads)
        short8 af[4], bf[4];
#pragma unroll
        for (int i = 0; i < 4; ++i)
            af[i] = *(const short8*)&Asm[cur][(wm * 64 + i * 16 + m16) * 32 + rc];
#pragma unroll
        for (int j = 0; j < 4; ++j)
            bf[j] = *(const short8*)&Bsm[cur][(wn * 64 + j * 16 + m16) * 32 + rc];
        __builtin_amdgcn_s_setprio(1);
#pragma unroll
        for (int i = 0; i < 4; ++i)
#pragma unroll
            for (int j = 0; j < 4; ++j)
                acc[i][j] = __builtin_amdgcn_mfma_f32_16x16x32_bf16(
                    af[i], bf[j], acc[i][j], 0, 0, 0);
        __builtin_amdgcn_s_setprio(0);
        // 3. next tile landed (own loads) + all waves done reading buf[cur]
        asm volatile("s_waitcnt vmcnt(0)" ::: "memory");
        __builtin_amdgcn_s_barrier();
        asm volatile("" ::: "memory");
        cur ^= 1;
    }
    // tail tile (staged + drained in last loop iteration)
    {
        short8 af[4], bf[4];
#pragma unroll
        for (int i = 0; i < 4; ++i)
            af[i] = *(const short8*)&Asm[cur][(wm * 64 + i * 16 + m16) * 32 + rc];
#pragma unroll
        for (int j = 0; j < 4; ++j)
            bf[j] = *(const short8*)&Bsm[cur][(wn * 64 + j * 16 + m16) * 32 + rc];
#pragma unroll
        for (int i = 0; i < 4; ++i)
#pragma unroll
            for (int j = 0; j < 4; ++j)
                acc[i][j] = __builtin_amdgcn_mfma_f32_16x16x32_bf16(
                    af[i], bf[j], acc[i][j], 0, 0, 0);
    }

    // epilogue
    float biasv[4];
#pragma unroll
    for (int j = 0; j < 4; ++j)
        biasv[j] = bias[col0 + wn * 64 + j * 16 + m16];
#pragma unroll
    for (int i = 0; i < 4; ++i) {
        const int rbaseo = row0 + wm * 64 + i * 16 + quad * 4;
#pragma unroll
        for (int reg = 0; reg < 4; ++reg) {
            const int rowg = rbaseo + reg;
            if (rowg >= M) continue;
#pragma unroll
            for (int j = 0; j < 4; ++j) {
                float t = acc[i][j][reg] + biasv[j];
                if (DO_GELU)
                    t = 0.5f * t * (1.0f + erff(t * 0.70710678118654752f));
                C[(size_t)rowg * N + col0 + wn * 64 + j * 16 + m16] = f2b(t);
            }
        }
    }
}

// ---------------------------------------------------------------------------
// MFMA attention (r5): block = (q-tile 64, head, batch), 256 thr = 4 waves.
// ---------------------------------------------------------------------------
__global__ __launch_bounds__(256) void attn_kernel(
    const u16* __restrict__ qkv, const float* __restrict__ rel,
    u16* __restrict__ outc) {
    const int qt = blockIdx.x, h = blockIdx.y, b = blockIdx.z;
    const int tid = threadIdx.x;
    const int lane = tid & 63, wave = tid >> 6;
    const int m16 = lane & 15, quad = lane >> 4;
    const int strip = wave * 16;

    __shared__ u16 Qs[64 * 72];
    __shared__ u16 Ks[64 * 72];
    __shared__ u16 Vt[64 * 72 + 48];
    __shared__ u16 Ps[64 * 72];
    __shared__ float relS[132];

    const size_t base = (size_t)(b * S_) * 3072 + h * 64;
    const int m  = tid >> 2;          // staging token 0..63
    const int d0 = (tid & 3) << 4;    // 0,16,32,48

    // stage Q tile (row-major [qrow][dim])
    {
        const int qg = qt * 64 + m;
        ushort8 v0 = {0, 0, 0, 0, 0, 0, 0, 0};
        ushort8 v1 = {0, 0, 0, 0, 0, 0, 0, 0};
        if (qg < S_) {
            const u16* gp = qkv + base + (size_t)qg * 3072;
            v0 = *(const ushort8*)(gp + d0);
            v1 = *(const ushort8*)(gp + d0 + 8);
        }
        *(ushort8*)&Qs[m * 72 + d0]     = v0;
        *(ushort8*)&Qs[m * 72 + d0 + 8] = v1;
    }
    if (tid < 129) relS[tid] = rel[tid * 16 + h];
    __syncthreads();

    const short8 qa0 = *(const short8*)&Qs[(strip + m16) * 72 + quad * 8];
    const short8 qa1 = *(const short8*)&Qs[(strip + m16) * 72 + 32 + quad * 8];

    f32x4 O[4];
#pragma unroll
    for (int n = 0; n < 4; ++n) O[n] = (f32x4){0.f, 0.f, 0.f, 0.f};
    float lrun[4] = {0.f, 0.f, 0.f, 0.f};

    for (int kt = 0; kt < 9; ++kt) {
        __syncthreads();   // prev iter's frag reads of Ks/Vt/Ps done
        // stage K (row-major) and V (transposed+skewed)
        {
            const int kg = kt * 64 + m;
            const int kvalid = (kg < S_);
            ushort8 k0 = {0, 0, 0, 0, 0, 0, 0, 0};
            ushort8 k1 = {0, 0, 0, 0, 0, 0, 0, 0};
            ushort8 w0 = {0, 0, 0, 0, 0, 0, 0, 0};
            ushort8 w1 = {0, 0, 0, 0, 0, 0, 0, 0};
            if (kvalid) {
                const u16* gk = qkv + base + (size_t)kg * 3072 + 1024;
                k0 = *(const ushort8*)(gk + d0);
                k1 = *(const ushort8*)(gk + d0 + 8);
                const u16* gv = qkv + base + (size_t)kg * 3072 + 2048;
                w0 = *(const ushort8*)(gv + d0);
                w1 = *(const ushort8*)(gv + d0 + 8);
            }
            *(ushort8*)&Ks[m * 72 + d0]     = k0;
            *(ushort8*)&Ks[m * 72 + d0 + 8] = k1;
#pragma unroll
            for (int i = 0; i < 8; ++i) {
                const int da = d0 + i;
                Vt[da * 72 + (da >> 4) * 16 + m] = (u16)w0[i];
                const int db = d0 + 8 + i;
                Vt[db * 72 + (db >> 4) * 16 + m] = (u16)w1[i];
            }
        }
        __syncthreads();

        // QK^T: sc[j] covers keys 16j..16j+15 for this wave's 16 q-rows
        f32x4 sc[4];
#pragma unroll
        for (int j = 0; j < 4; ++j) {
            const short8 kb0 = *(const short8*)&Ks[(16 * j + m16) * 72 + quad * 8];
            const short8 kb1 = *(const short8*)&Ks[(16 * j + m16) * 72 + 32 + quad * 8];
            f32x4 z = (f32x4){0.f, 0.f, 0.f, 0.f};
            z = __builtin_amdgcn_mfma_f32_16x16x32_bf16(qa0, kb0, z, 0, 0, 0);
            sc[j] = __builtin_amdgcn_mfma_f32_16x16x32_bf16(qa1, kb1, z, 0, 0, 0);
        }

        // softmax numerators (identical math to passing version), -> bf16
        const int qg0 = qt * 64 + strip + quad * 4;
        float ps[4] = {0.f, 0.f, 0.f, 0.f};
#pragma unroll
        for (int j = 0; j < 4; ++j) {
            const int kg = kt * 64 + 16 * j + m16;
            const int kvalid = (kg < S_);
#pragma unroll
            for (int reg = 0; reg < 4; ++reg) {
                int rr = kg - (qg0 + reg);
                rr = rr < -64 ? -64 : (rr > 64 ? 64 : rr);
                float s = sc[j][reg] * 0.125f + relS[rr + 64];
                s = s > 60.f ? 60.f : s;
                float pv = kvalid ? __expf(s) : 0.f;
                const u16 pb = f2b(pv);
                Ps[(strip + quad * 4 + reg) * 72 + 16 * j + m16] = pb;
                ps[reg] += b2f(pb);   // denominator from rounded P (consistent)
            }
        }
#pragma unroll
        for (int mk = 1; mk < 16; mk <<= 1) {
#pragma unroll
            for (int reg = 0; reg < 4; ++reg)
                ps[reg] += __shfl_xor(ps[reg], mk);
        }
#pragma unroll
        for (int reg = 0; reg < 4; ++reg) lrun[reg] += ps[reg];
        __syncthreads();   // Ps visible

        // PV: O[n] (dims 16n..16n+15) += P @ V
        const short8 pa0 = *(const short8*)&Ps[(strip + m16) * 72 + quad * 8];
        const short8 pa1 = *(const short8*)&Ps[(strip + m16) * 72 + 32 + quad * 8];
#pragma unroll
        for (int n = 0; n < 4; ++n) {
            const int dd = 16 * n + m16;
            const int vbase = dd * 72 + (dd >> 4) * 16;
            const short8 vb0 = *(const short8*)&Vt[vbase + quad * 8];
            const short8 vb1 = *(const short8*)&Vt[vbase + 32 + quad * 8];
            O[n] = __builtin_amdgcn_mfma_f32_16x16x32_bf16(pa0, vb0, O[n], 0, 0, 0);
            O[n] = __builtin_amdgcn_mfma_f32_16x16x32_bf16(pa1, vb1, O[n], 0, 0, 0);
        }
    }

    // epilogue: normalize + store (lrun[reg] is exactly this lane's O rows)
#pragma unroll
    for (int reg = 0; reg < 4; ++reg) {
        const int qg = qt * 64 + strip + quad * 4 + reg;
        if (qg >= S_) continue;
        const float inv = 1.0f / lrun[reg];
        u16* op = outc + (size_t)(b * S_ + qg) * D_ + h * 64;
#pragma unroll
        for (int n = 0; n < 4; ++n)
            op[16 * n + m16] = f2b(O[n][reg] * inv);
    }
}

// ---------------------------------------------------------------------------
// add_ln: x fp32 (residual) + Bv bf16 -> LN -> x fp32 AND xh bf16
// ---------------------------------------------------------------------------
__global__ __launch_bounds__(256) void add_ln_kernel(
    const float* __restrict__ A, const u16* __restrict__ Bv,
    const float* __restrict__ g, const float* __restrict__ be,
    float* __restrict__ outp, u16* __restrict__ outh) {
    const int row = blockIdx.x;
    const int tid = threadIdx.x;
    __shared__ float r1[256], r2[256];
    float4 a = *(const float4*)(A + (size_t)row * D_ + tid * 4);
    ushort4 b4 = *(const ushort4*)(Bv + (size_t)row * D_ + tid * 4);
    const float v0 = a.x + b2f(b4.x), v1 = a.y + b2f(b4.y);
    const float v2 = a.z + b2f(b4.z), v3 = a.w + b2f(b4.w);
    r1[tid] = v0 + v1 + v2 + v3;
    r2[tid] = v0 * v0 + v1 * v1 + v2 * v2 + v3 * v3;
    __syncthreads();
#pragma unroll
    for (int off = 128; off > 0; off >>= 1) {
        if (tid < off) { r1[tid] += r1[tid + off]; r2[tid] += r2[tid + off]; }
        __syncthreads();
    }
    const float mu = r1[0] * (1.0f / 1024.0f);
    const float var = r2[0] * (1.0f / 1024.0f) - mu * mu;
    const float rs = rsqrtf(var + 1e-5f);
    float4 gv = *(const float4*)(g + tid * 4);
    float4 bev = *(const float4*)(be + tid * 4);
    float4 o = make_float4((v0 - mu) * rs * gv.x + bev.x,
                           (v1 - mu) * rs * gv.y + bev.y,
                           (v2 - mu) * rs * gv.z + bev.z,
                           (v3 - mu) * rs * gv.w + bev.w);
    *(float4*)(outp + (size_t)row * D_ + tid * 4) = o;
    ushort4 oh;
    oh.x = f2b(o.x); oh.y = f2b(o.y); oh.z = f2b(o.z); oh.w = f2b(o.w);
    *(ushort4*)(outh + (size_t)row * D_ + tid * 4) = oh;
}

// ---------------------------------------------------------------------------
__global__ __launch_bounds__(256) void head_kernel(
    const int* __restrict__ flagp,
    const float* __restrict__ x, const float* __restrict__ g,
    const float* __restrict__ be, const float* __restrict__ cw,
    const float* __restrict__ cb, void* __restrict__ outp) {
    const int b = blockIdx.x, tid = threadIdx.x;
    __shared__ float xn[D_];
    __shared__ float r1[256], r2[256];
    const float* xr = x + (size_t)b * S_ * D_;
    float4 v = *(const float4*)(xr + tid * 4);
    r1[tid] = v.x + v.y + v.z + v.w;
    r2[tid] = v.x * v.x + v.y * v.y + v.z * v.z + v.w * v.w;
    __syncthreads();
#pragma unroll
    for (int off = 128; off > 0; off >>= 1) {
        if (tid < off) { r1[tid] += r1[tid + off]; r2[tid] += r2[tid + off]; }
        __syncthreads();
    }
    const float mu = r1[0] * (1.0f / 1024.0f);
    const float var = r2[0] * (1.0f / 1024.0f) - mu * mu;
    const float rs = rsqrtf(var + 1e-5f);
    float4 gv = *(const float4*)(g + tid * 4);
    float4 bev = *(const float4*)(be + tid * 4);
    xn[tid * 4 + 0] = (v.x - mu) * rs * gv.x + bev.x;
    xn[tid * 4 + 1] = (v.y - mu) * rs * gv.y + bev.y;
    xn[tid * 4 + 2] = (v.z - mu) * rs * gv.z + bev.z;
    xn[tid * 4 + 3] = (v.w - mu) * rs * gv.w + bev.w;
    __syncthreads();
    if (tid < 80) {
        float acc = cb[tid];
        for (int dd = 0; dd < D_; ++dd)
            acc = fmaf(xn[dd], cw[dd * 80 + tid], acc);
        if (*flagp) ((float*)outp)[b * 80 + tid] = acc;
        else        ((u16*)outp)[b * 80 + tid] = f2b(acc);
    }
}

// ---------------------------------------------------------------------------
extern "C" void kernel_launch(void* const* d_in, const int* in_sizes, int n_in,
                              void* d_out, int out_size, void* d_ws, size_t ws_size,
                              hipStream_t stream) {
    const int* src = (const int*)d_in[0];
    (void)in_sizes; (void)n_in; (void)out_size; (void)ws_size;

    char* p = (char*)d_ws;
    auto carve = [&](size_t bytes) {
        char* r = p; p += (bytes + 255) & ~(size_t)255; return r;
    };
    int*   flag = (int*)carve(256);
    float* x    = (float*)carve((size_t)BS_ * D_ * 4);   // fp32 residual
    u16*   xh   = (u16*)carve((size_t)BS_ * D_ * 2);     // bf16 copy of x
    u16*   big  = (u16*)carve((size_t)BS_ * FF_ * 2);    // qkv / ff1 out
    u16*   t1   = (u16*)carve((size_t)BS_ * D_ * 2);     // attn out / ff2 out
    u16*   Wt   = (u16*)carve((size_t)FF_ * D_ * 2);     // transposed weight
    int*   dpos = (int*)carve((size_t)B_ * L_ * 4);
    u16*   t2   = big;                                   // proj out (aliases)

    const int PN[17]  = {16*D_, S_*D_, L_*D_, D_,
                         NL_*3*D_, NL_*D_, NL_*129*16,
                         NL_*D_, NL_*D_, NL_*FF_, NL_*D_,
                         NL_*D_, NL_*D_, D_, D_,
                         D_*80, 80};
    const int PIN[17] = {2, 3, 4, 5, 7, 9, 10, 11, 12, 14, 16, 17, 18,
                         19, 20, 21, 22};
    float* P[17];
    {
        size_t off = 0;
        float* base = (float*)carve(1243312 * 4);
        for (int i = 0; i < 17; ++i) { P[i] = base + off; off += PN[i]; }
    }
    float *Ptok = P[0], *Ppos = P[1], *Pdig = P[2], *Pcls = P[3];
    float *Pqkvb = P[4], *Poutb = P[5], *Prel = P[6];
    float *Pln1g = P[7], *Pln1b = P[8], *Pl1b = P[9], *Pl2b = P[10];
    float *Pln2g = P[11], *Pln2b = P[12], *Pfng = P[13], *Pfnb = P[14];
    float *Pcw = P[15], *Pcb = P[16];

    probe_kernel<<<1, 256, 0, stream>>>((const u16*)d_in[6], flag);
    for (int i = 0; i < 17; ++i)
        cvt_kernel<<<(PN[i] + 255) / 256, 256, 0, stream>>>(
            flag, d_in[PIN[i]], P[i], PN[i]);

    dpos_kernel<<<B_, L_, 0, stream>>>(src, dpos);
    embed_kernel<<<BS_, 256, 0, stream>>>(src, dpos, Ptok, Ppos, Pdig, Pcls,
                                          x, xh);

    const int gy = (BS_ + 127) / 128;   // 33
    for (int l = 0; l < NL_; ++l) {
        // qkv = xh @ qkv_w + b
        transp_kernel<<<dim3(D_ / 32, 3 * D_ / 32), 256, 0, stream>>>(
            flag, d_in[6], (size_t)l * D_ * 3 * D_, Wt, D_, 3 * D_);
        gemm_mfma<0><<<dim3(3 * D_ / 128, gy), 256, 0, stream>>>(
            xh, Wt, Pqkvb + (size_t)l * 3 * D_, big, BS_, 3 * D_, D_);
        attn_kernel<<<dim3(9, H_, B_), 256, 0, stream>>>(
            big, Prel + (size_t)l * 129 * 16, t1);
        // proj = t1 @ out_w + b  -> t2 (= big region, qkv dead)
        transp_kernel<<<dim3(D_ / 32, D_ / 32), 256, 0, stream>>>(
            flag, d_in[8], (size_t)l * D_ * D_, Wt, D_, D_);
        gemm_mfma<0><<<dim3(D_ / 128, gy), 256, 0, stream>>>(
            t1, Wt, Poutb + (size_t)l * D_, t2, BS_, D_, D_);
        add_ln_kernel<<<BS_, 256, 0, stream>>>(x, t2, Pln1g + l * D_,
                                               Pln1b + l * D_, x, xh);
        // ff1 = gelu(xh @ lin1_w + b) -> big (t2 dead)
        transp_kernel<<<dim3(D_ / 32, FF_ / 32), 256, 0, stream>>>(
            flag, d_in[13], (size_t)l * D_ * FF_, Wt, D_, FF_);
        gemm_mfma<1><<<dim3(FF_ / 128, gy), 256, 0, stream>>>(
            xh, Wt, Pl1b + (size_t)l * FF_, big, BS_, FF_, D_);
        // ff2 = big @ lin2_w + b -> t1 (attn out dead)
        transp_kernel<<<dim3(FF_ / 32, D_ / 32), 256, 0, stream>>>(
            flag, d_in[15], (size_t)l * FF_ * D_, Wt, FF_, D_);
        gemm_mfma<0><<<dim3(D_ / 128, gy), 256, 0, stream>>>(
            big, Wt, Pl2b + (size_t)l * D_, t1, BS_, D_, FF_);
        add_ln_kernel<<<BS_, 256, 0, stream>>>(x, t1, Pln2g + l * D_,
                                               Pln2b + l * D_, x, xh);
    }
    head_kernel<<<B_, 256, 0, stream>>>(flag, x, Pfng, Pfnb, Pcw, Pcb, d_out);
}

// Round 6
// 2078.813 us; speedup vs baseline: 1.1629x; 1.0810x over previous
//
#include <hip/hip_runtime.h>
#include <hip/hip_bf16.h>
#include <math.h>

#define B_  8
#define L_  512
#define D_  1024
#define H_  16
#define NL_ 6
#define FF_ 4096
#define S_  513
#define BS_ (B_*S_)   // 4104 rows

typedef unsigned short u16;
typedef __attribute__((ext_vector_type(8))) short    short8;
typedef __attribute__((ext_vector_type(8))) unsigned short ushort8;
typedef __attribute__((ext_vector_type(4))) float    f32x4;

__device__ __forceinline__ float b2f(u16 u) {
    return __uint_as_float(((unsigned int)u) << 16);
}
__device__ __forceinline__ u16 f2b(float f) {
    unsigned int u = __float_as_uint(f);
    u += 0x7fffu + ((u >> 16) & 1u);   // round-to-nearest-even
    return (u16)(u >> 16);
}

// direct global->LDS DMA, 16B per lane (dest = wave-uniform base + lane*16)
__device__ __forceinline__ void gld_lds16(const u16* g, u16* l) {
    __builtin_amdgcn_global_load_lds(
        (const __attribute__((address_space(1))) void*)g,
        (__attribute__((address_space(3))) void*)l, 16, 0, 0);
}

// ---------------------------------------------------------------------------
// Dtype probe (flag=1: float inputs are fp32 on device — measured round 3)
// ---------------------------------------------------------------------------
__global__ __launch_bounds__(256) void probe_kernel(const u16* __restrict__ buf,
                                                    int* __restrict__ flagp) {
    __shared__ int cnt[256];
    const int tid = threadIdx.x;
    const float a = fabsf(b2f(buf[tid]));
    cnt[tid] = (a >= 1e-8f && a <= 100.0f) ? 1 : 0;
    __syncthreads();
#pragma unroll
    for (int off = 128; off > 0; off >>= 1) {
        if (tid < off) cnt[tid] += cnt[tid + off];
        __syncthreads();
    }
    if (tid == 0) *flagp = (cnt[0] < 200) ? 1 : 0;
}

// ---------------------------------------------------------------------------
// Fused parameter convert: one launch for all 17 segments (was 17 launches).
// blockIdx.y = segment; compile-time size/offset tables (wave-uniform index).
// ---------------------------------------------------------------------------
struct CvtSrc { const void* p[17]; };

__global__ __launch_bounds__(256) void cvt_all_kernel(
    const int* __restrict__ flagp, CvtSrc srcs, float* __restrict__ d) {
    constexpr int PNc[17]  = {16*D_, S_*D_, L_*D_, D_,
                              NL_*3*D_, NL_*D_, NL_*129*16,
                              NL_*D_, NL_*D_, NL_*FF_, NL_*D_,
                              NL_*D_, NL_*D_, D_, D_,
                              D_*80, 80};
    constexpr int OFFc[17] = {0, 16384, 541696, 1065984, 1067008, 1085440,
                              1091584, 1103968, 1110112, 1116256, 1140832,
                              1146976, 1153120, 1159264, 1160288, 1161312,
                              1243232};
    const int seg = blockIdx.y;
    const int i = blockIdx.x * 256 + threadIdx.x;
    if (i >= PNc[seg]) return;
    const int wf = *flagp;
    const void* s = srcs.p[seg];
    d[OFFc[seg] + i] = wf ? ((const float*)s)[i] : b2f(((const u16*)s)[i]);
}

// ---------------------------------------------------------------------------
// Transpose+convert weights: Wt[n][k] (bf16) = W[k][n] (fp32 or bf16)
// 32x32 tiles, 256 threads (32x8), LDS pad +1.
// ---------------------------------------------------------------------------
__global__ __launch_bounds__(256) void transp_kernel(
    const int* __restrict__ flagp, const void* __restrict__ Wbase, size_t Woff,
    u16* __restrict__ Wt, int K, int N) {
    __shared__ float tile[32][33];
    const int wf = *flagp;
    const int tid = threadIdx.x;
    const int tx = tid & 31, ty = tid >> 5;      // 32 x 8
    const int kt = blockIdx.x * 32, nt = blockIdx.y * 32;
    const float* Wf = (const float*)Wbase + Woff;
    const u16*   Wh = (const u16*)Wbase + Woff;
#pragma unroll
    for (int p = 0; p < 4; ++p) {
        const int k = kt + ty + p * 8;
        const size_t idx = (size_t)k * N + nt + tx;
        tile[ty + p * 8][tx] = wf ? Wf[idx] : b2f(Wh[idx]);
    }
    __syncthreads();
#pragma unroll
    for (int p = 0; p < 4; ++p) {
        const int n = nt + ty + p * 8;
        Wt[(size_t)n * K + kt + tx] = f2b(tile[tx][ty + p * 8]);
    }
}

// ---------------------------------------------------------------------------
__global__ __launch_bounds__(512) void dpos_kernel(const int* __restrict__ src,
                                                   int* __restrict__ dpos) {
    const int b = blockIdx.x;
    const int i = threadIdx.x;
    __shared__ int s[L_];
    s[i] = src[b * L_ + i];
    __syncthreads();
    int r = -1;
    if (s[i] < 10) {
        int j = i + 1;
        while (j < L_ && s[j] < 10) ++j;
        r = j - i - 1;
    }
    dpos[b * L_ + i] = r;
}

// ---------------------------------------------------------------------------
// embed: writes x (fp32) and xh (bf16 copy for MFMA A-operand)
// ---------------------------------------------------------------------------
__global__ __launch_bounds__(256) void embed_kernel(
    const int* __restrict__ src, const int* __restrict__ dpos,
    const float* __restrict__ tok, const float* __restrict__ pos,
    const float* __restrict__ dig, const float* __restrict__ cls,
    float* __restrict__ x, u16* __restrict__ xh) {
    const int row = blockIdx.x;          // b*S + s
    const int b = row / S_, s = row % S_;
    const int d = threadIdx.x * 4;
    float4 o;
    if (s == 0) {
        o = *(const float4*)(cls + d);
    } else {
        float4 tv = *(const float4*)(tok + (size_t)src[b * L_ + s - 1] * D_ + d);
        float4 pv = *(const float4*)(pos + (size_t)(s - 1) * D_ + d);
        o = make_float4(tv.x + pv.x, tv.y + pv.y, tv.z + pv.z, tv.w + pv.w);
        const int dp = dpos[b * L_ + s - 1];
        if (dp >= 0) {
            float4 dv = *(const float4*)(dig + (size_t)dp * D_ + d);
            o.x += dv.x; o.y += dv.y; o.z += dv.z; o.w += dv.w;
        }
    }
    *(float4*)(x + (size_t)row * D_ + d) = o;
    ushort4 oh;
    oh.x = f2b(o.x); oh.y = f2b(o.y); oh.z = f2b(o.z); oh.w = f2b(o.w);
    *(ushort4*)(xh + (size_t)row * D_ + d) = oh;
}

// ---------------------------------------------------------------------------
// MFMA GEMM (r2-proven, best measured at 128²): 128x128 tile, BK=64, 4 waves,
// single-buffered LDS, stage -> sync -> ds_read+32 MFMA -> sync.
// Swizzle chunk^=row&7 both-sides; XCD chunked swizzle (nwg%8==0 grids only).
// ---------------------------------------------------------------------------
template <int DO_GELU>
__global__ __launch_bounds__(256) void gemm_mfma(
    const u16* __restrict__ A, const u16* __restrict__ Wt,
    const float* __restrict__ bias, u16* __restrict__ C,
    int M, int N, int K) {
    __shared__ u16 Asm[128 * 64];
    __shared__ u16 Bsm[128 * 64];
    const int tid = threadIdx.x;
    const int lane = tid & 63, wave = tid >> 6;
    const int wm = wave >> 1, wn = wave & 1;
    const int m16 = lane & 15, quad = lane >> 4;

    const int gx = gridDim.x;
    const int nwg = gx * gridDim.y;        // multiple of 8 for these grids
    const int bid = blockIdx.y * gx + blockIdx.x;
    const int cpx = nwg >> 3;
    const int swz = (bid & 7) * cpx + (bid >> 3);
    const int row0 = (swz / gx) * 128, col0 = (swz % gx) * 128;

    const int sr     = lane >> 3;          // 0..7
    const int chunk  = lane & 7;           // 16B chunk within 128B row
    const int schunk = chunk ^ sr;         // pre-swizzled source chunk
    const int rbase  = wave * 8 + sr;      // LDS row 0..31 (+32 per pass)

    f32x4 acc[4][4];
#pragma unroll
    for (int i = 0; i < 4; ++i)
#pragma unroll
        for (int j = 0; j < 4; ++j)
            acc[i][j] = (f32x4){0.f, 0.f, 0.f, 0.f};

    for (int k0 = 0; k0 < K; k0 += 64) {
#pragma unroll
        for (int p = 0; p < 4; ++p) {
            const int rr = p * 32 + rbase;            // LDS row 0..127
            int ga = row0 + rr;                        // A row (clamped tail)
            if (ga >= M) ga = M - 1;
            gld_lds16(A + (size_t)ga * K + k0 + schunk * 8,
                      Asm + p * 2048 + wave * 512);
            gld_lds16(Wt + (size_t)(col0 + rr) * K + k0 + schunk * 8,
                      Bsm + p * 2048 + wave * 512);
        }
        __syncthreads();   // drains vmcnt (compiler emits waitcnt before barrier)

        const int sw = m16 & 7;
        short8 af[4][2], bf[4][2];
#pragma unroll
        for (int i = 0; i < 4; ++i)
#pragma unroll
            for (int h = 0; h < 2; ++h)
                af[i][h] = *(const short8*)&Asm[(wm * 64 + i * 16 + m16) * 64 +
                                                (((h << 2) + quad) ^ sw) * 8];
#pragma unroll
        for (int j = 0; j < 4; ++j)
#pragma unroll
            for (int h = 0; h < 2; ++h)
                bf[j][h] = *(const short8*)&Bsm[(wn * 64 + j * 16 + m16) * 64 +
                                                (((h << 2) + quad) ^ sw) * 8];
#pragma unroll
        for (int i = 0; i < 4; ++i)
#pragma unroll
            for (int j = 0; j < 4; ++j) {
                acc[i][j] = __builtin_amdgcn_mfma_f32_16x16x32_bf16(
                    af[i][0], bf[j][0], acc[i][j], 0, 0, 0);
                acc[i][j] = __builtin_amdgcn_mfma_f32_16x16x32_bf16(
                    af[i][1], bf[j][1], acc[i][j], 0, 0, 0);
            }
        __syncthreads();
    }
    // epilogue
    float biasv[4];
#pragma unroll
    for (int j = 0; j < 4; ++j)
        biasv[j] = bias[col0 + wn * 64 + j * 16 + m16];
#pragma unroll
    for (int i = 0; i < 4; ++i) {
        const int rbaseo = row0 + wm * 64 + i * 16 + quad * 4;
#pragma unroll
        for (int reg = 0; reg < 4; ++reg) {
            const int rowg = rbaseo + reg;
            if (rowg >= M) continue;
#pragma unroll
            for (int j = 0; j < 4; ++j) {
                float t = acc[i][j][reg] + biasv[j];
                if (DO_GELU)
                    t = 0.5f * t * (1.0f + erff(t * 0.70710678118654752f));
                C[(size_t)rowg * N + col0 + wn * 64 + j * 16 + m16] = f2b(t);
            }
        }
    }
}

// ---------------------------------------------------------------------------
// WIDE MFMA GEMM: 128x256 tile, 512 thr = 8 waves (2 wm x 4 wn of 64x64),
// BK=64, single-buffered LDS A[128][64]+B[256][64] = 48KB (3 blocks/CU).
// Same r2-proven schedule/swizzle/fragment code; 2x MFMA per block-step
// against the same stage+drain+barrier cost, half the total block-steps
// (tile-size lever for K=1024 regime; m230-V0/m248v2 ~660-680 TF basis).
// Used only where grid >= ~256 blocks (ff1: 528, qkv: 396).
// Bijective XCD swizzle (handles nwg%8 != 0, ERRATA #11 formula).
// ---------------------------------------------------------------------------
template <int DO_GELU>
__global__ __launch_bounds__(512) void gemm_wide(
    const u16* __restrict__ A, const u16* __restrict__ Wt,
    const float* __restrict__ bias, u16* __restrict__ C,
    int M, int N, int K) {
    __shared__ u16 Asm[128 * 64];
    __shared__ u16 Bsm[256 * 64];
    const int tid = threadIdx.x;
    const int lane = tid & 63, wave = tid >> 6;
    const int wm = wave >> 2, wn = wave & 3;
    const int m16 = lane & 15, quad = lane >> 4;

    // bijective XCD-aware swizzle
    const int gx = gridDim.x;
    const int nwg = gx * gridDim.y;
    const int bid = blockIdx.y * gx + blockIdx.x;
    const int qq = nwg >> 3, r8 = nwg & 7;
    const int xcd = bid & 7, idx = bid >> 3;
    const int swz = (xcd < r8 ? xcd * (qq + 1)
                              : r8 * (qq + 1) + (xcd - r8) * qq) + idx;
    const int row0 = (swz / gx) * 128, col0 = (swz % gx) * 256;

    const int sr     = lane >> 3;          // 0..7
    const int chunk  = lane & 7;
    const int schunk = (chunk ^ sr) * 8;   // pre-swizzled source chunk (u16)

    f32x4 acc[4][4];
#pragma unroll
    for (int i = 0; i < 4; ++i)
#pragma unroll
        for (int j = 0; j < 4; ++j)
            acc[i][j] = (f32x4){0.f, 0.f, 0.f, 0.f};

    // staging pointers: A rows p*64 + wave*8 + sr (p<2); B rows (p<4)
    const u16* aptr[2];
    const u16* bptr[4];
#pragma unroll
    for (int p = 0; p < 2; ++p) {
        int ga = row0 + p * 64 + wave * 8 + sr;
        if (ga >= M) ga = M - 1;
        aptr[p] = A + (size_t)ga * K + schunk;
    }
#pragma unroll
    for (int p = 0; p < 4; ++p)
        bptr[p] = Wt + (size_t)(col0 + p * 64 + wave * 8 + sr) * K + schunk;

    for (int k0 = 0; k0 < K; k0 += 64) {
        gld_lds16(aptr[0] + k0, Asm + wave * 512);
        gld_lds16(aptr[1] + k0, Asm + 4096 + wave * 512);
#pragma unroll
        for (int p = 0; p < 4; ++p)
            gld_lds16(bptr[p] + k0, Bsm + p * 4096 + wave * 512);
        __syncthreads();

        const int sw = m16 & 7;
        short8 af[4][2], bf[4][2];
#pragma unroll
        for (int i = 0; i < 4; ++i)
#pragma unroll
            for (int h = 0; h < 2; ++h)
                af[i][h] = *(const short8*)&Asm[(wm * 64 + i * 16 + m16) * 64 +
                                                (((h << 2) + quad) ^ sw) * 8];
#pragma unroll
        for (int j = 0; j < 4; ++j)
#pragma unroll
            for (int h = 0; h < 2; ++h)
                bf[j][h] = *(const short8*)&Bsm[(wn * 64 + j * 16 + m16) * 64 +
                                                (((h << 2) + quad) ^ sw) * 8];
#pragma unroll
        for (int i = 0; i < 4; ++i)
#pragma unroll
            for (int j = 0; j < 4; ++j) {
                acc[i][j] = __builtin_amdgcn_mfma_f32_16x16x32_bf16(
                    af[i][0], bf[j][0], acc[i][j], 0, 0, 0);
                acc[i][j] = __builtin_amdgcn_mfma_f32_16x16x32_bf16(
                    af[i][1], bf[j][1], acc[i][j], 0, 0, 0);
            }
        __syncthreads();
    }
    // epilogue
    float biasv[4];
#pragma unroll
    for (int j = 0; j < 4; ++j)
        biasv[j] = bias[col0 + wn * 64 + j * 16 + m16];
#pragma unroll
    for (int i = 0; i < 4; ++i) {
        const int rbaseo = row0 + wm * 64 + i * 16 + quad * 4;
#pragma unroll
        for (int reg = 0; reg < 4; ++reg) {
            const int rowg = rbaseo + reg;
            if (rowg >= M) continue;
#pragma unroll
            for (int j = 0; j < 4; ++j) {
                float t = acc[i][j][reg] + biasv[j];
                if (DO_GELU)
                    t = 0.5f * t * (1.0f + erff(t * 0.70710678118654752f));
                C[(size_t)rowg * N + col0 + wn * 64 + j * 16 + m16] = f2b(t);
            }
        }
    }
}

// ---------------------------------------------------------------------------
// MFMA attention (r5): block = (q-tile 64, head, batch), 256 thr = 4 waves.
// ---------------------------------------------------------------------------
__global__ __launch_bounds__(256) void attn_kernel(
    const u16* __restrict__ qkv, const float* __restrict__ rel,
    u16* __restrict__ outc) {
    const int qt = blockIdx.x, h = blockIdx.y, b = blockIdx.z;
    const int tid = threadIdx.x;
    const int lane = tid & 63, wave = tid >> 6;
    const int m16 = lane & 15, quad = lane >> 4;
    const int strip = wave * 16;

    __shared__ u16 Qs[64 * 72];
    __shared__ u16 Ks[64 * 72];
    __shared__ u16 Vt[64 * 72 + 48];
    __shared__ u16 Ps[64 * 72];
    __shared__ float relS[132];

    const size_t base = (size_t)(b * S_) * 3072 + h * 64;
    const int m  = tid >> 2;          // staging token 0..63
    const int d0 = (tid & 3) << 4;    // 0,16,32,48

    // stage Q tile (row-major [qrow][dim])
    {
        const int qg = qt * 64 + m;
        ushort8 v0 = {0, 0, 0, 0, 0, 0, 0, 0};
        ushort8 v1 = {0, 0, 0, 0, 0, 0, 0, 0};
        if (qg < S_) {
            const u16* gp = qkv + base + (size_t)qg * 3072;
            v0 = *(const ushort8*)(gp + d0);
            v1 = *(const ushort8*)(gp + d0 + 8);
        }
        *(ushort8*)&Qs[m * 72 + d0]     = v0;
        *(ushort8*)&Qs[m * 72 + d0 + 8] = v1;
    }
    if (tid < 129) relS[tid] = rel[tid * 16 + h];
    __syncthreads();

    const short8 qa0 = *(const short8*)&Qs[(strip + m16) * 72 + quad * 8];
    const short8 qa1 = *(const short8*)&Qs[(strip + m16) * 72 + 32 + quad * 8];

    f32x4 O[4];
#pragma unroll
    for (int n = 0; n < 4; ++n) O[n] = (f32x4){0.f, 0.f, 0.f, 0.f};
    float lrun[4] = {0.f, 0.f, 0.f, 0.f};

    for (int kt = 0; kt < 9; ++kt) {
        __syncthreads();   // prev iter's frag reads of Ks/Vt/Ps done
        // stage K (row-major) and V (transposed+skewed)
        {
            const int kg = kt * 64 + m;
            const int kvalid = (kg < S_);
            ushort8 k0 = {0, 0, 0, 0, 0, 0, 0, 0};
            ushort8 k1 = {0, 0, 0, 0, 0, 0, 0, 0};
            ushort8 w0 = {0, 0, 0, 0, 0, 0, 0, 0};
            ushort8 w1 = {0, 0, 0, 0, 0, 0, 0, 0};
            if (kvalid) {
                const u16* gk = qkv + base + (size_t)kg * 3072 + 1024;
                k0 = *(const ushort8*)(gk + d0);
                k1 = *(const ushort8*)(gk + d0 + 8);
                const u16* gv = qkv + base + (size_t)kg * 3072 + 2048;
                w0 = *(const ushort8*)(gv + d0);
                w1 = *(const ushort8*)(gv + d0 + 8);
            }
            *(ushort8*)&Ks[m * 72 + d0]     = k0;
            *(ushort8*)&Ks[m * 72 + d0 + 8] = k1;
#pragma unroll
            for (int i = 0; i < 8; ++i) {
                const int da = d0 + i;
                Vt[da * 72 + (da >> 4) * 16 + m] = (u16)w0[i];
                const int db = d0 + 8 + i;
                Vt[db * 72 + (db >> 4) * 16 + m] = (u16)w1[i];
            }
        }
        __syncthreads();

        // QK^T: sc[j] covers keys 16j..16j+15 for this wave's 16 q-rows
        f32x4 sc[4];
#pragma unroll
        for (int j = 0; j < 4; ++j) {
            const short8 kb0 = *(const short8*)&Ks[(16 * j + m16) * 72 + quad * 8];
            const short8 kb1 = *(const short8*)&Ks[(16 * j + m16) * 72 + 32 + quad * 8];
            f32x4 z = (f32x4){0.f, 0.f, 0.f, 0.f};
            z = __builtin_amdgcn_mfma_f32_16x16x32_bf16(qa0, kb0, z, 0, 0, 0);
            sc[j] = __builtin_amdgcn_mfma_f32_16x16x32_bf16(qa1, kb1, z, 0, 0, 0);
        }

        // softmax numerators (identical math to passing version), -> bf16
        const int qg0 = qt * 64 + strip + quad * 4;
        float ps[4] = {0.f, 0.f, 0.f, 0.f};
#pragma unroll
        for (int j = 0; j < 4; ++j) {
            const int kg = kt * 64 + 16 * j + m16;
            const int kvalid = (kg < S_);
#pragma unroll
            for (int reg = 0; reg < 4; ++reg) {
                int rr = kg - (qg0 + reg);
                rr = rr < -64 ? -64 : (rr > 64 ? 64 : rr);
                float s = sc[j][reg] * 0.125f + relS[rr + 64];
                s = s > 60.f ? 60.f : s;
                float pv = kvalid ? __expf(s) : 0.f;
                const u16 pb = f2b(pv);
                Ps[(strip + quad * 4 + reg) * 72 + 16 * j + m16] = pb;
                ps[reg] += b2f(pb);   // denominator from rounded P (consistent)
            }
        }
#pragma unroll
        for (int mk = 1; mk < 16; mk <<= 1) {
#pragma unroll
            for (int reg = 0; reg < 4; ++reg)
                ps[reg] += __shfl_xor(ps[reg], mk);
        }
#pragma unroll
        for (int reg = 0; reg < 4; ++reg) lrun[reg] += ps[reg];
        __syncthreads();   // Ps visible

        // PV: O[n] (dims 16n..16n+15) += P @ V
        const short8 pa0 = *(const short8*)&Ps[(strip + m16) * 72 + quad * 8];
        const short8 pa1 = *(const short8*)&Ps[(strip + m16) * 72 + 32 + quad * 8];
#pragma unroll
        for (int n = 0; n < 4; ++n) {
            const int dd = 16 * n + m16;
            const int vbase = dd * 72 + (dd >> 4) * 16;
            const short8 vb0 = *(const short8*)&Vt[vbase + quad * 8];
            const short8 vb1 = *(const short8*)&Vt[vbase + 32 + quad * 8];
            O[n] = __builtin_amdgcn_mfma_f32_16x16x32_bf16(pa0, vb0, O[n], 0, 0, 0);
            O[n] = __builtin_amdgcn_mfma_f32_16x16x32_bf16(pa1, vb1, O[n], 0, 0, 0);
        }
    }

    // epilogue: normalize + store (lrun[reg] is exactly this lane's O rows)
#pragma unroll
    for (int reg = 0; reg < 4; ++reg) {
        const int qg = qt * 64 + strip + quad * 4 + reg;
        if (qg >= S_) continue;
        const float inv = 1.0f / lrun[reg];
        u16* op = outc + (size_t)(b * S_ + qg) * D_ + h * 64;
#pragma unroll
        for (int n = 0; n < 4; ++n)
            op[16 * n + m16] = f2b(O[n][reg] * inv);
    }
}

// ---------------------------------------------------------------------------
// add_ln: x fp32 (residual) + Bv bf16 -> LN -> x fp32 AND xh bf16
// ---------------------------------------------------------------------------
__global__ __launch_bounds__(256) void add_ln_kernel(
    const float* __restrict__ A, const u16* __restrict__ Bv,
    const float* __restrict__ g, const float* __restrict__ be,
    float* __restrict__ outp, u16* __restrict__ outh) {
    const int row = blockIdx.x;
    const int tid = threadIdx.x;
    __shared__ float r1[256], r2[256];
    float4 a = *(const float4*)(A + (size_t)row * D_ + tid * 4);
    ushort4 b4 = *(const ushort4*)(Bv + (size_t)row * D_ + tid * 4);
    const float v0 = a.x + b2f(b4.x), v1 = a.y + b2f(b4.y);
    const float v2 = a.z + b2f(b4.z), v3 = a.w + b2f(b4.w);
    r1[tid] = v0 + v1 + v2 + v3;
    r2[tid] = v0 * v0 + v1 * v1 + v2 * v2 + v3 * v3;
    __syncthreads();
#pragma unroll
    for (int off = 128; off > 0; off >>= 1) {
        if (tid < off) { r1[tid] += r1[tid + off]; r2[tid] += r2[tid + off]; }
        __syncthreads();
    }
    const float mu = r1[0] * (1.0f / 1024.0f);
    const float var = r2[0] * (1.0f / 1024.0f) - mu * mu;
    const float rs = rsqrtf(var + 1e-5f);
    float4 gv = *(const float4*)(g + tid * 4);
    float4 bev = *(const float4*)(be + tid * 4);
    float4 o = make_float4((v0 - mu) * rs * gv.x + bev.x,
                           (v1 - mu) * rs * gv.y + bev.y,
                           (v2 - mu) * rs * gv.z + bev.z,
                           (v3 - mu) * rs * gv.w + bev.w);
    *(float4*)(outp + (size_t)row * D_ + tid * 4) = o;
    ushort4 oh;
    oh.x = f2b(o.x); oh.y = f2b(o.y); oh.z = f2b(o.z); oh.w = f2b(o.w);
    *(ushort4*)(outh + (size_t)row * D_ + tid * 4) = oh;
}

// ---------------------------------------------------------------------------
__global__ __launch_bounds__(256) void head_kernel(
    const int* __restrict__ flagp,
    const float* __restrict__ x, const float* __restrict__ g,
    const float* __restrict__ be, const float* __restrict__ cw,
    const float* __restrict__ cb, void* __restrict__ outp) {
    const int b = blockIdx.x, tid = threadIdx.x;
    __shared__ float xn[D_];
    __shared__ float r1[256], r2[256];
    const float* xr = x + (size_t)b * S_ * D_;
    float4 v = *(const float4*)(xr + tid * 4);
    r1[tid] = v.x + v.y + v.z + v.w;
    r2[tid] = v.x * v.x + v.y * v.y + v.z * v.z + v.w * v.w;
    __syncthreads();
#pragma unroll
    for (int off = 128; off > 0; off >>= 1) {
        if (tid < off) { r1[tid] += r1[tid + off]; r2[tid] += r2[tid + off]; }
        __syncthreads();
    }
    const float mu = r1[0] * (1.0f / 1024.0f);
    const float var = r2[0] * (1.0f / 1024.0f) - mu * mu;
    const float rs = rsqrtf(var + 1e-5f);
    float4 gv = *(const float4*)(g + tid * 4);
    float4 bev = *(const float4*)(be + tid * 4);
    xn[tid * 4 + 0] = (v.x - mu) * rs * gv.x + bev.x;
    xn[tid * 4 + 1] = (v.y - mu) * rs * gv.y + bev.y;
    xn[tid * 4 + 2] = (v.z - mu) * rs * gv.z + bev.z;
    xn[tid * 4 + 3] = (v.w - mu) * rs * gv.w + bev.w;
    __syncthreads();
    if (tid < 80) {
        float acc = cb[tid];
        for (int dd = 0; dd < D_; ++dd)
            acc = fmaf(xn[dd], cw[dd * 80 + tid], acc);
        if (*flagp) ((float*)outp)[b * 80 + tid] = acc;
        else        ((u16*)outp)[b * 80 + tid] = f2b(acc);
    }
}

// ---------------------------------------------------------------------------
extern "C" void kernel_launch(void* const* d_in, const int* in_sizes, int n_in,
                              void* d_out, int out_size, void* d_ws, size_t ws_size,
                              hipStream_t stream) {
    const int* src = (const int*)d_in[0];
    (void)in_sizes; (void)n_in; (void)out_size; (void)ws_size;

    char* p = (char*)d_ws;
    auto carve = [&](size_t bytes) {
        char* r = p; p += (bytes + 255) & ~(size_t)255; return r;
    };
    int*   flag = (int*)carve(256);
    float* x    = (float*)carve((size_t)BS_ * D_ * 4);   // fp32 residual
    u16*   xh   = (u16*)carve((size_t)BS_ * D_ * 2);     // bf16 copy of x
    u16*   big  = (u16*)carve((size_t)BS_ * FF_ * 2);    // qkv / ff1 out
    u16*   t1   = (u16*)carve((size_t)BS_ * D_ * 2);     // attn out / ff2 out
    u16*   Wt   = (u16*)carve((size_t)FF_ * D_ * 2);     // transposed weight
    int*   dpos = (int*)carve((size_t)B_ * L_ * 4);
    u16*   t2   = big;                                   // proj out (aliases)

    const int PN[17]  = {16*D_, S_*D_, L_*D_, D_,
                         NL_*3*D_, NL_*D_, NL_*129*16,
                         NL_*D_, NL_*D_, NL_*FF_, NL_*D_,
                         NL_*D_, NL_*D_, D_, D_,
                         D_*80, 80};
    const int PIN[17] = {2, 3, 4, 5, 7, 9, 10, 11, 12, 14, 16, 17, 18,
                         19, 20, 21, 22};
    float* P[17];
    {
        size_t off = 0;
        float* base = (float*)carve(1243312 * 4);
        for (int i = 0; i < 17; ++i) { P[i] = base + off; off += PN[i]; }
    }
    float *Ptok = P[0], *Ppos = P[1], *Pdig = P[2], *Pcls = P[3];
    float *Pqkvb = P[4], *Poutb = P[5], *Prel = P[6];
    float *Pln1g = P[7], *Pln1b = P[8], *Pl1b = P[9], *Pl2b = P[10];
    float *Pln2g = P[11], *Pln2b = P[12], *Pfng = P[13], *Pfnb = P[14];
    float *Pcw = P[15], *Pcb = P[16];

    probe_kernel<<<1, 256, 0, stream>>>((const u16*)d_in[6], flag);
    {
        CvtSrc cs;
        for (int i = 0; i < 17; ++i) cs.p[i] = d_in[PIN[i]];
        cvt_all_kernel<<<dim3((S_ * D_ + 255) / 256, 17), 256, 0, stream>>>(
            flag, cs, P[0]);
    }

    dpos_kernel<<<B_, L_, 0, stream>>>(src, dpos);
    embed_kernel<<<BS_, 256, 0, stream>>>(src, dpos, Ptok, Ppos, Pdig, Pcls,
                                          x, xh);

    const int gy = (BS_ + 127) / 128;   // 33
    for (int l = 0; l < NL_; ++l) {
        // qkv = xh @ qkv_w + b   (wide: N=3072 -> 12x33 = 396 blocks)
        transp_kernel<<<dim3(D_ / 32, 3 * D_ / 32), 256, 0, stream>>>(
            flag, d_in[6], (size_t)l * D_ * 3 * D_, Wt, D_, 3 * D_);
        gemm_wide<0><<<dim3(3 * D_ / 256, gy), 512, 0, stream>>>(
            xh, Wt, Pqkvb + (size_t)l * 3 * D_, big, BS_, 3 * D_, D_);
        attn_kernel<<<dim3(9, H_, B_), 256, 0, stream>>>(
            big, Prel + (size_t)l * 129 * 16, t1);
        // proj = t1 @ out_w + b  -> t2 (= big region, qkv dead)  (128² r2)
        transp_kernel<<<dim3(D_ / 32, D_ / 32), 256, 0, stream>>>(
            flag, d_in[8], (size_t)l * D_ * D_, Wt, D_, D_);
        gemm_mfma<0><<<dim3(D_ / 128, gy), 256, 0, stream>>>(
            t1, Wt, Poutb + (size_t)l * D_, t2, BS_, D_, D_);
        add_ln_kernel<<<BS_, 256, 0, stream>>>(x, t2, Pln1g + l * D_,
                                               Pln1b + l * D_, x, xh);
        // ff1 = gelu(xh @ lin1_w + b) -> big   (wide: 16x33 = 528 blocks)
        transp_kernel<<<dim3(D_ / 32, FF_ / 32), 256, 0, stream>>>(
            flag, d_in[13], (size_t)l * D_ * FF_, Wt, D_, FF_);
        gemm_wide<1><<<dim3(FF_ / 256, gy), 512, 0, stream>>>(
            xh, Wt, Pl1b + (size_t)l * FF_, big, BS_, FF_, D_);
        // ff2 = big @ lin2_w + b -> t1 (attn out dead)  (128² r2)
        transp_kernel<<<dim3(FF_ / 32, D_ / 32), 256, 0, stream>>>(
            flag, d_in[15], (size_t)l * FF_ * D_, Wt, FF_, D_);
        gemm_mfma<0><<<dim3(D_ / 128, gy), 256, 0, stream>>>(
            big, Wt, Pl2b + (size_t)l * D_, t1, BS_, D_, FF_);
        add_ln_kernel<<<BS_, 256, 0, stream>>>(x, t1, Pln2g + l * D_,
                                               Pln2b + l * D_, x, xh);
    }
    head_kernel<<<B_, 256, 0, stream>>>(flag, x, Pfng, Pfnb, Pcw, Pcb, d_out);
}